// Round 4
// baseline (3914.605 us; speedup 1.0000x reference)
//
#include <hip/hip_runtime.h>

#define E_NODES 62
#define TOPK 10
// conv geometry: (5,64) -> c1 5x5 -> (1,60) -> pool -> 30
//                -> c2 1x5 (64ch) -> 26 -> pool -> 13
//                -> c3 1x5 (128ch) -> 9 -> pool -> 4 (pos 8 unused)

// ================= fused conv chain =================
// 256 threads / block, 4 images (wave = image). Writes H3 (31744,512).
// LDS floats: img[4][320]@0 | h1[4][32][32]@1280 | h2[4][64][20]@5376
//             wchunk[64][41]@10496 | b2[64]@13120 | b3[128]@13184
// total 13312 floats = 52 KB -> 3 blocks/CU
// __launch_bounds__(256,3): REQUIRED — without it compiler hits 196 VGPR
// -> 1 wave/SIMD -> 12% occupancy (round-3 regression).

__global__ __launch_bounds__(256, 3) void conv_chain_kernel(
    const float* __restrict__ x,
    const float* __restrict__ w1, const float* __restrict__ b1,
    const float* __restrict__ w2, const float* __restrict__ b2,
    const float* __restrict__ w3, const float* __restrict__ b3,
    float* __restrict__ H3)
{
  __shared__ float sm[13312];
  float* s_img = sm;            // 4*320
  float* s_h1  = sm + 1280;     // 4*32*32 (pitch 32; conflict-free via lane=tp writes)
  float* s_h2  = sm + 5376;     // 4*64*20 (pitch 20; aligned float4 reads)
  float* s_w   = sm + 10496;    // 64*41 = 2624 chunk buffer (w1's 832 fits too)
  float* s_b2  = sm + 13120;    // 64
  float* s_b3  = sm + 13184;    // 128

  const int tid = threadIdx.x;
  const int n0 = blockIdx.x * 4;
  const int im = tid >> 6;
  const int lane = tid & 63;

  for (int i = tid; i < 1280; i += 256) s_img[i] = x[(size_t)n0 * 320 + i];
  for (int i = tid; i < 832; i += 256) s_w[i] = (i < 800) ? w1[i] : b1[i - 800];
  for (int i = tid; i < 192; i += 256) {
    if (i < 64) s_b2[i] = b2[i]; else s_b3[i - 64] = b3[i - 64];
  }
  __syncthreads();

  // ---- conv1 + relu + pool. lane = (half, tp): stride-1 writes (no conflict)
  {
    const int tp = lane & 31;        // pooled position, 0..29 used
    const int half = lane >> 5;      // output-channel half
    if (tp < 30) {
      const float* ib = s_img + im * 320;
      const int t0 = 2 * tp;
      float r[5][6];
#pragma unroll
      for (int kr = 0; kr < 5; ++kr)
#pragma unroll
        for (int c = 0; c < 6; ++c) r[kr][c] = ib[kr * 64 + t0 + c];
#pragma unroll
      for (int oi = 0; oi < 16; ++oi) {
        const int o = half * 16 + oi;
        const float* w = s_w + o * 25;        // 2-address broadcast reads
        const float bia = s_w[800 + o];
        float s0 = bia, s1 = bia;
#pragma unroll
        for (int kr = 0; kr < 5; ++kr) {
#pragma unroll
          for (int k = 0; k < 5; ++k) {
            const float wv = w[kr * 5 + k];
            s0 += r[kr][k] * wv;
            s1 += r[kr][k + 1] * wv;
          }
        }
        s_h1[im * 1024 + o * 32 + tp] = fmaxf(fmaxf(s0, s1), 0.f);
      }
    }
  }

  // ---- conv2 + relu + pool: thread = (im, o); weights chunked 8 ci
  {
    const int o = lane;
    float acc0[13], acc1[13];
    const float bia = s_b2[o];
#pragma unroll
    for (int t = 0; t < 13; ++t) { acc0[t] = bia; acc1[t] = bia; }
#pragma unroll 1
    for (int c = 0; c < 4; ++c) {
      __syncthreads();
      for (int i = tid; i < 2560; i += 256) {
        const int oo = i / 40, rr = i - oo * 40;
        s_w[oo * 41 + rr] = w2[oo * 160 + c * 40 + rr];
      }
      __syncthreads();
#pragma unroll
      for (int cl = 0; cl < 8; ++cl) {
        const int ci = c * 8 + cl;
        const float* hr = s_h1 + im * 1024 + ci * 32;   // wave-broadcast, 16B-aligned
        float r[30];
#pragma unroll
        for (int q = 0; q < 7; ++q) {
          const float4 v = *(const float4*)(hr + q * 4);
          r[q * 4] = v.x; r[q * 4 + 1] = v.y; r[q * 4 + 2] = v.z; r[q * 4 + 3] = v.w;
        }
        { const float2 v = *(const float2*)(hr + 28); r[28] = v.x; r[29] = v.y; }
        const float* w = s_w + o * 41 + cl * 5;         // 41 coprime 32: conflict-free
        const float w0 = w[0], w1_ = w[1], w2_ = w[2], w3_ = w[3], w4_ = w[4];
#pragma unroll
        for (int t = 0; t < 13; ++t) {
          const int t0 = 2 * t;
          acc0[t] += r[t0] * w0 + r[t0 + 1] * w1_ + r[t0 + 2] * w2_ + r[t0 + 3] * w3_ + r[t0 + 4] * w4_;
          acc1[t] += r[t0 + 1] * w0 + r[t0 + 2] * w1_ + r[t0 + 3] * w2_ + r[t0 + 4] * w3_ + r[t0 + 5] * w4_;
        }
      }
    }
    __syncthreads();
#pragma unroll
    for (int t = 0; t < 13; ++t)
      s_h2[im * 1280 + o * 20 + t] = fmaxf(fmaxf(acc0[t], acc1[t]), 0.f);  // 8-way on 13 writes: minor
  }

  // ---- conv3 + relu + pool -> H3 global (coalesced float4)
  {
    const int oc = lane;
#pragma unroll 1
    for (int ch = 0; ch < 2; ++ch) {
      float acc[8];
      const float bia = s_b3[ch * 64 + oc];
#pragma unroll
      for (int t = 0; t < 8; ++t) acc[t] = bia;
#pragma unroll 1
      for (int c = 0; c < 8; ++c) {
        __syncthreads();
        for (int i = tid; i < 2560; i += 256) {
          const int oo = i / 40, rr = i - oo * 40;
          s_w[oo * 41 + rr] = w3[(ch * 64 + oo) * 320 + c * 40 + rr];
        }
        __syncthreads();
#pragma unroll
        for (int cl = 0; cl < 8; ++cl) {
          const int ci = c * 8 + cl;
          const float* hr = s_h2 + im * 1280 + ci * 20;  // wave-broadcast, aligned
          float r[12];
#pragma unroll
          for (int q = 0; q < 3; ++q) {
            const float4 v = *(const float4*)(hr + q * 4);
            r[q * 4] = v.x; r[q * 4 + 1] = v.y; r[q * 4 + 2] = v.z; r[q * 4 + 3] = v.w;
          }
          const float* w = s_w + oc * 41 + cl * 5;
          const float w0 = w[0], w1_ = w[1], w2_ = w[2], w3_ = w[3], w4_ = w[4];
#pragma unroll
          for (int t = 0; t < 8; ++t)
            acc[t] += r[t] * w0 + r[t + 1] * w1_ + r[t + 2] * w2_ + r[t + 3] * w3_ + r[t + 4] * w4_;
        }
      }
      float4 ov;
      ov.x = fmaxf(fmaxf(acc[0], acc[1]), 0.f);
      ov.y = fmaxf(fmaxf(acc[2], acc[3]), 0.f);
      ov.z = fmaxf(fmaxf(acc[4], acc[5]), 0.f);
      ov.w = fmaxf(fmaxf(acc[6], acc[7]), 0.f);
      *(float4*)(H3 + (size_t)(n0 + im) * 512 + (size_t)(ch * 64 + oc) * 4) = ov;
    }
  }
}

// ================= GP projection: GP[n][0:32)=tanh(Wbn1.h), [32:96)=gc1w.h ==========
// block = 32 images, 256 threads; thread = (im=tid>>3, oq=tid&7) -> 12 outputs each.
__global__ __launch_bounds__(256) void gp_kernel(
    const float* __restrict__ H3, const float* __restrict__ Wbn1,
    const float* __restrict__ gc1w, float* __restrict__ GP)
{
  __shared__ float sH[32 * 65];   // pitch 65
  __shared__ float sW[96 * 65];
  const int tid = threadIdx.x;
  const int n0 = blockIdx.x * 32;
  const int im = tid >> 3;
  const int oq = tid & 7;

  float acc[12];
#pragma unroll
  for (int j = 0; j < 12; ++j) acc[j] = 0.f;

#pragma unroll 1
  for (int c8 = 0; c8 < 8; ++c8) {
    const int d0 = c8 * 64;
    __syncthreads();
    for (int i = tid; i < 2048; i += 256) {
      const int r = i >> 6, cc = i & 63;
      sH[r * 65 + cc] = H3[(size_t)(n0 + r) * 512 + d0 + cc];   // coalesced
    }
    for (int i = tid; i < 6144; i += 256) {
      const int o = i >> 6, cc = i & 63;
      sW[o * 65 + cc] = (o < 32) ? Wbn1[o * 512 + d0 + cc]
                                 : gc1w[(o - 32) * 512 + d0 + cc];
    }
    __syncthreads();
#pragma unroll 4
    for (int d = 0; d < 64; ++d) {
      const float h = sH[im * 65 + d];     // 8 addrs/wave: conflict-free
#pragma unroll
      for (int j = 0; j < 12; ++j)
        acc[j] += h * sW[(oq * 12 + j) * 65 + d];   // 8 distinct banks
    }
  }
  float* gpo = GP + (size_t)(n0 + im) * 96;
#pragma unroll
  for (int j = 0; j < 12; ++j) {
    const int o = oq * 12 + j;
    gpo[o] = (o < 32) ? (1.f - 2.f / (__expf(2.f * acc[j]) + 1.f)) : acc[j];
  }
}

// ================= SOGC layer 1 (consumes GP) =================
__global__ __launch_bounds__(256) void sogc1_kernel(
    const float* __restrict__ GP, const float* __restrict__ gcb,
    float* __restrict__ Hout)
{
  __shared__ float sG[62 * 33];
  __shared__ float sP[62 * 64];
  __shared__ float stv[620];
  __shared__ int   sti[620];
  const int b = blockIdx.x, tid = threadIdx.x;
  const int lane = tid & 63, wave = tid >> 6;

  const float* gp = GP + (size_t)b * 62 * 96;
  for (int i = tid; i < 62 * 96; i += 256) {
    const int e = i / 96, q = i - e * 96;
    const float v = gp[i];
    if (q < 32) sG[e * 33 + q] = v; else sP[e * 64 + (q - 32)] = v;
  }
  __syncthreads();

  for (int e = wave; e < E_NODES; e += 4) {
    float sc = -1e30f;
    if (lane < E_NODES) {
      float s = 0.f;
#pragma unroll
      for (int k = 0; k < 32; ++k) s += sG[e * 33 + k] * sG[lane * 33 + k];
      sc = s;
    }
    float mx = sc;
#pragma unroll
    for (int off = 32; off; off >>= 1) mx = fmaxf(mx, __shfl_xor(mx, off));
    float p = (lane < E_NODES) ? __expf(sc - mx) : 0.f;
    float sum = p;
#pragma unroll
    for (int off = 32; off; off >>= 1) sum += __shfl_xor(sum, off);
    p = p / sum;
    float v = (lane < E_NODES) ? p : -1.f;
#pragma unroll 1
    for (int it = 0; it < TOPK; ++it) {
      float bv = v; int bi = lane;
#pragma unroll
      for (int off = 32; off; off >>= 1) {
        const float ov = __shfl_xor(bv, off);
        const int   oi = __shfl_xor(bi, off);
        if (ov > bv || (ov == bv && oi < bi)) { bv = ov; bi = oi; }  // lax.top_k tie-break
      }
      if (lane == 0) { stv[e * 10 + it] = bv; sti[e * 10 + it] = bi; }
      if (lane == bi) v = -1.f;
    }
  }
  __syncthreads();

  for (int e = wave; e < E_NODES; e += 4) {
    float acc = gcb[lane];
#pragma unroll
    for (int j = 0; j < TOPK; ++j)
      acc += stv[e * 10 + j] * sP[sti[e * 10 + j] * 64 + lane];
    Hout[((size_t)b * E_NODES + e) * 64 + lane] = fmaxf(acc, 0.f);
  }
}

// ================= SOGC layers 2/3 (DIN=64), cls fused into layer 3 =================
template <bool CLS>
__global__ __launch_bounds__(256) void sogc64_kernel(
    const float* __restrict__ Hin, const float* __restrict__ Wbn,
    const float* __restrict__ gcw, const float* __restrict__ gcb,
    const float* __restrict__ cw, const float* __restrict__ cb,
    float* __restrict__ outbuf)   // Hout (b,62,64) or logits (b,4)
{
  extern __shared__ float sm[];
  float* sH  = sm;                 // 62*65 = 4030
  float* sWt = sm + 4030;          // 64*97 = 6208
  float* sG  = sm + 10238;         // 62*33 = 2046
  float* sP  = sm + 12284;         // 62*64 = 3968
  float* stv = sm + 16252;         // 620
  int*   sti = (int*)(sm + 16872); // 620
  float* sred = sm + 17492;        // 16

  const int b = blockIdx.x, tid = threadIdx.x;
  const int lane = tid & 63, wave = tid >> 6;

  const float* Hb = Hin + (size_t)b * 62 * 64;
  for (int i = tid; i < 62 * 64; i += 256)
    sH[(i >> 6) * 65 + (i & 63)] = Hb[i];
  for (int i = tid; i < 64 * 64; i += 256)        // gcw (o,d) -> sWt[d][o]
    sWt[(i & 63) * 97 + (i >> 6)] = gcw[i];
  for (int i = tid; i < 32 * 64; i += 256)        // Wbn (k,d) -> sWt[d][64+k]
    sWt[(i & 63) * 97 + 64 + (i >> 6)] = Wbn[i];
  __syncthreads();

  for (int e = wave; e < E_NODES; e += 4) {
    const float* hrow = sH + e * 65;
    const float* wp = sWt + lane;
    const float* wg = sWt + 64 + (lane & 31);
    float accp = 0.f, accg = 0.f;
#pragma unroll 8
    for (int d = 0; d < 64; ++d) {
      const float h = hrow[d];
      accp += h * wp[d * 97];
      accg += h * wg[d * 97];
    }
    sP[e * 64 + lane] = accp;
    if (lane < 32) sG[e * 33 + lane] = 1.f - 2.f / (__expf(2.f * accg) + 1.f);
  }
  __syncthreads();

  for (int e = wave; e < E_NODES; e += 4) {
    float sc = -1e30f;
    if (lane < E_NODES) {
      float s = 0.f;
#pragma unroll
      for (int k = 0; k < 32; ++k) s += sG[e * 33 + k] * sG[lane * 33 + k];
      sc = s;
    }
    float mx = sc;
#pragma unroll
    for (int off = 32; off; off >>= 1) mx = fmaxf(mx, __shfl_xor(mx, off));
    float p = (lane < E_NODES) ? __expf(sc - mx) : 0.f;
    float sum = p;
#pragma unroll
    for (int off = 32; off; off >>= 1) sum += __shfl_xor(sum, off);
    p = p / sum;
    float v = (lane < E_NODES) ? p : -1.f;
#pragma unroll 1
    for (int it = 0; it < TOPK; ++it) {
      float bv = v; int bi = lane;
#pragma unroll
      for (int off = 32; off; off >>= 1) {
        const float ov = __shfl_xor(bv, off);
        const int   oi = __shfl_xor(bi, off);
        if (ov > bv || (ov == bv && oi < bi)) { bv = ov; bi = oi; }
      }
      if (lane == 0) { stv[e * 10 + it] = bv; sti[e * 10 + it] = bi; }
      if (lane == bi) v = -1.f;
    }
  }
  __syncthreads();

  float accn[4] = {0.f, 0.f, 0.f, 0.f};
  for (int e = wave; e < E_NODES; e += 4) {
    float acc = gcb[lane];
#pragma unroll
    for (int j = 0; j < TOPK; ++j)
      acc += stv[e * 10 + j] * sP[sti[e * 10 + j] * 64 + lane];
    acc = fmaxf(acc, 0.f);
    if (CLS) {
#pragma unroll
      for (int n = 0; n < 4; ++n)
        accn[n] += acc * cw[n * 3968 + e * 64 + lane];
    } else {
      outbuf[((size_t)b * E_NODES + e) * 64 + lane] = acc;
    }
  }
  if (CLS) {
#pragma unroll
    for (int n = 0; n < 4; ++n) {
      float s = accn[n];
#pragma unroll
      for (int off = 32; off; off >>= 1) s += __shfl_xor(s, off);
      if (lane == 0) sred[wave * 4 + n] = s;
    }
    __syncthreads();
    if (tid < 4)
      outbuf[b * 4 + tid] = cb[tid] + sred[tid] + sred[4 + tid] + sred[8 + tid] + sred[12 + tid];
  }
}

// ================= launch =================
extern "C" void kernel_launch(void* const* d_in, const int* in_sizes, int n_in,
                              void* d_out, int out_size, void* d_ws, size_t ws_size,
                              hipStream_t stream) {
  const float* x    = (const float*)d_in[0];
  const float* c1w  = (const float*)d_in[1];
  const float* c1b  = (const float*)d_in[2];
  const float* c2w  = (const float*)d_in[3];
  const float* c2b  = (const float*)d_in[4];
  const float* c3w  = (const float*)d_in[5];
  const float* c3b  = (const float*)d_in[6];
  const float* Wbn1 = (const float*)d_in[7];
  const float* gc1w = (const float*)d_in[8];
  const float* gc1b = (const float*)d_in[9];
  const float* Wbn2 = (const float*)d_in[10];
  const float* gc2w = (const float*)d_in[11];
  const float* gc2b = (const float*)d_in[12];
  const float* Wbn3 = (const float*)d_in[13];
  const float* gc3w = (const float*)d_in[14];
  const float* gc3b = (const float*)d_in[15];
  const float* clsw = (const float*)d_in[16];
  const float* clsb = (const float*)d_in[17];
  float* out = (float*)d_out;

  float* wsf = (float*)d_ws;
  float* H3  = wsf;                         // 31744*512 = 16,252,928 floats
  float* GP  = wsf + (size_t)16252928;      // 31744*96 = 3,047,424
  float* Hs1 = GP + (size_t)3047424;        // 512*62*64 = 2,031,616
  float* Hs2 = Hs1 + (size_t)2031616;       // total ~93 MB

  const int SOGC64_BYTES = 17508 * 4;       // 70,032 B dynamic LDS

  (void)hipFuncSetAttribute((const void*)sogc64_kernel<false>,
                            hipFuncAttributeMaxDynamicSharedMemorySize, SOGC64_BYTES);
  (void)hipFuncSetAttribute((const void*)sogc64_kernel<true>,
                            hipFuncAttributeMaxDynamicSharedMemorySize, SOGC64_BYTES);

  conv_chain_kernel<<<7936, 256, 0, stream>>>(x, c1w, c1b, c2w, c2b, c3w, c3b, H3);
  gp_kernel<<<992, 256, 0, stream>>>(H3, Wbn1, gc1w, GP);
  sogc1_kernel<<<512, 256, 0, stream>>>(GP, gc1b, Hs1);
  sogc64_kernel<false><<<512, 256, SOGC64_BYTES, stream>>>(
      Hs1, Wbn2, gc2w, gc2b, nullptr, nullptr, Hs2);
  sogc64_kernel<true><<<512, 256, SOGC64_BYTES, stream>>>(
      Hs2, Wbn3, gc3w, gc3b, clsw, clsb, out);
}

// Round 5
// 1517.310 us; speedup vs baseline: 2.5800x; 2.5800x over previous
//
#include <hip/hip_runtime.h>

#define E_NODES 62
#define TOPK 10
// conv geometry: (5,64) -> c1 5x5 -> (1,60) -> pool -> 30
//                -> c2 1x5 (64ch) -> 26 -> pool -> 13
//                -> c3 1x5 (128ch) -> 9 -> pool -> 4 (pos 8 unused)

// ================= fused conv chain =================
// 256 threads / block, 4 images (wave = image). Writes H3 (31744,512).
// LDS floats: img[4][320]@0 | h1[4][32][32]@1280 | h2[4][64][20]@5376
//             wchunk[64][41]@10496 | b2[64]@13120 | b3[128]@13184
// total 13312 floats = 52 KB -> 3 blocks/CU.
// Register budget model (round-2/3/4 evidence): unified file 512/wave;
// __launch_bounds__(256,3) caps VGPR+AGPR at ~170. Round-3 natural live set
// was 196 -> bound caused 14 GB scratch spill. Fix: conv2 t-tiled (7+6)
// so natural live ~50 floats -> fits the cap with NO spills.

__global__ __launch_bounds__(256, 3) void conv_chain_kernel(
    const float* __restrict__ x,
    const float* __restrict__ w1, const float* __restrict__ b1,
    const float* __restrict__ w2, const float* __restrict__ b2,
    const float* __restrict__ w3, const float* __restrict__ b3,
    float* __restrict__ H3)
{
  __shared__ float sm[13312];
  float* s_img = sm;            // 4*320
  float* s_h1  = sm + 1280;     // 4*32*32 (pitch 32; conflict-free lane=tp writes)
  float* s_h2  = sm + 5376;     // 4*64*20 (pitch 20)
  float* s_w   = sm + 10496;    // 64*41 = 2624 chunk buffer
  float* s_b2  = sm + 13120;    // 64
  float* s_b3  = sm + 13184;    // 128

  const int tid = threadIdx.x;
  const int n0 = blockIdx.x * 4;
  const int im = tid >> 6;
  const int lane = tid & 63;

  for (int i = tid; i < 1280; i += 256) s_img[i] = x[(size_t)n0 * 320 + i];
  for (int i = tid; i < 832; i += 256) s_w[i] = (i < 800) ? w1[i] : b1[i - 800];
  for (int i = tid; i < 192; i += 256) {
    if (i < 64) s_b2[i] = b2[i]; else s_b3[i - 64] = b3[i - 64];
  }
  __syncthreads();

  // ---- conv1 + relu + pool. lane = (half, tp): stride-1 writes (no conflict)
  {
    const int tp = lane & 31;        // pooled position, 0..29 used
    const int half = lane >> 5;      // output-channel half
    if (tp < 30) {
      const float* ib = s_img + im * 320;
      const int t0 = 2 * tp;
      float r[5][6];
#pragma unroll
      for (int kr = 0; kr < 5; ++kr)
#pragma unroll
        for (int c = 0; c < 6; ++c) r[kr][c] = ib[kr * 64 + t0 + c];
#pragma unroll 4
      for (int oi = 0; oi < 16; ++oi) {
        const int o = half * 16 + oi;
        const float* w = s_w + o * 25;        // 2-address broadcast reads
        const float bia = s_w[800 + o];
        float s0 = bia, s1 = bia;
#pragma unroll
        for (int kr = 0; kr < 5; ++kr) {
#pragma unroll
          for (int k = 0; k < 5; ++k) {
            const float wv = w[kr * 5 + k];
            s0 += r[kr][k] * wv;
            s1 += r[kr][k + 1] * wv;
          }
        }
        s_h1[im * 1024 + o * 32 + tp] = fmaxf(fmaxf(s0, s1), 0.f);
      }
    }
  }

  // ---- conv2 + relu + pool: thread = (im, o). T-TILED (t=0..6, then 7..12)
  // to keep the live set ~50 floats (spill-free under the 3-wave cap).
  {
    const int o = lane;
    const float bia = s_b2[o];

    // ---- tile 0: pooled t = 0..6 (raw 0..13, inputs 0..17)
    {
      float acc0[7], acc1[7];
#pragma unroll
      for (int t = 0; t < 7; ++t) { acc0[t] = bia; acc1[t] = bia; }
#pragma unroll 1
      for (int c = 0; c < 4; ++c) {
        __syncthreads();
        for (int i = tid; i < 2560; i += 256) {
          const int oo = i / 40, rr = i - oo * 40;
          s_w[oo * 41 + rr] = w2[oo * 160 + c * 40 + rr];
        }
        __syncthreads();
#pragma unroll 4
        for (int cl = 0; cl < 8; ++cl) {
          const int ci = c * 8 + cl;
          const float* hr = s_h1 + im * 1024 + ci * 32;   // wave-broadcast, aligned
          float r[18];
#pragma unroll
          for (int q = 0; q < 4; ++q) {
            const float4 v = *(const float4*)(hr + q * 4);
            r[q * 4] = v.x; r[q * 4 + 1] = v.y; r[q * 4 + 2] = v.z; r[q * 4 + 3] = v.w;
          }
          r[16] = hr[16]; r[17] = hr[17];
          const float* w = s_w + o * 41 + cl * 5;         // stride 41: conflict-free
          const float w0 = w[0], w1_ = w[1], w2_ = w[2], w3_ = w[3], w4_ = w[4];
#pragma unroll
          for (int t = 0; t < 7; ++t) {
            const int t0 = 2 * t;
            acc0[t] += r[t0] * w0 + r[t0 + 1] * w1_ + r[t0 + 2] * w2_ + r[t0 + 3] * w3_ + r[t0 + 4] * w4_;
            acc1[t] += r[t0 + 1] * w0 + r[t0 + 2] * w1_ + r[t0 + 3] * w2_ + r[t0 + 4] * w3_ + r[t0 + 5] * w4_;
          }
        }
      }
#pragma unroll
      for (int t = 0; t < 7; ++t)
        s_h2[im * 1280 + o * 20 + t] = fmaxf(fmaxf(acc0[t], acc1[t]), 0.f);
    }

    // ---- tile 1: pooled t = 7..12 (raw 14..25, inputs 14..29; load 12..29)
    {
      float acc0[6], acc1[6];
#pragma unroll
      for (int t = 0; t < 6; ++t) { acc0[t] = bia; acc1[t] = bia; }
#pragma unroll 1
      for (int c = 0; c < 4; ++c) {
        __syncthreads();
        for (int i = tid; i < 2560; i += 256) {
          const int oo = i / 40, rr = i - oo * 40;
          s_w[oo * 41 + rr] = w2[oo * 160 + c * 40 + rr];
        }
        __syncthreads();
#pragma unroll 4
        for (int cl = 0; cl < 8; ++cl) {
          const int ci = c * 8 + cl;
          const float* hr = s_h1 + im * 1024 + ci * 32;
          float r[18];                                    // r[j] = input[12+j]
#pragma unroll
          for (int q = 0; q < 4; ++q) {
            const float4 v = *(const float4*)(hr + 12 + q * 4);
            r[q * 4] = v.x; r[q * 4 + 1] = v.y; r[q * 4 + 2] = v.z; r[q * 4 + 3] = v.w;
          }
          r[16] = hr[28]; r[17] = hr[29];
          const float* w = s_w + o * 41 + cl * 5;
          const float w0 = w[0], w1_ = w[1], w2_ = w[2], w3_ = w[3], w4_ = w[4];
#pragma unroll
          for (int t = 0; t < 6; ++t) {
            const int t0 = 2 * (t + 7) - 12;              // local index
            acc0[t] += r[t0] * w0 + r[t0 + 1] * w1_ + r[t0 + 2] * w2_ + r[t0 + 3] * w3_ + r[t0 + 4] * w4_;
            acc1[t] += r[t0 + 1] * w0 + r[t0 + 2] * w1_ + r[t0 + 3] * w2_ + r[t0 + 4] * w3_ + r[t0 + 5] * w4_;
          }
        }
      }
#pragma unroll
      for (int t = 0; t < 6; ++t)
        s_h2[im * 1280 + o * 20 + 7 + t] = fmaxf(fmaxf(acc0[t], acc1[t]), 0.f);
    }
  }

  // ---- conv3 + relu + pool -> H3 global (coalesced float4)
  {
    const int oc = lane;
#pragma unroll 1
    for (int ch = 0; ch < 2; ++ch) {
      float acc[8];
      const float bia = s_b3[ch * 64 + oc];
#pragma unroll
      for (int t = 0; t < 8; ++t) acc[t] = bia;
#pragma unroll 1
      for (int c = 0; c < 8; ++c) {
        __syncthreads();
        for (int i = tid; i < 2560; i += 256) {
          const int oo = i / 40, rr = i - oo * 40;
          s_w[oo * 41 + rr] = w3[(ch * 64 + oo) * 320 + c * 40 + rr];
        }
        __syncthreads();
#pragma unroll 4
        for (int cl = 0; cl < 8; ++cl) {
          const int ci = c * 8 + cl;
          const float* hr = s_h2 + im * 1280 + ci * 20;  // wave-broadcast, aligned
          float r[12];
#pragma unroll
          for (int q = 0; q < 3; ++q) {
            const float4 v = *(const float4*)(hr + q * 4);
            r[q * 4] = v.x; r[q * 4 + 1] = v.y; r[q * 4 + 2] = v.z; r[q * 4 + 3] = v.w;
          }
          const float* w = s_w + oc * 41 + cl * 5;
          const float w0 = w[0], w1_ = w[1], w2_ = w[2], w3_ = w[3], w4_ = w[4];
#pragma unroll
          for (int t = 0; t < 8; ++t)
            acc[t] += r[t] * w0 + r[t + 1] * w1_ + r[t + 2] * w2_ + r[t + 3] * w3_ + r[t + 4] * w4_;
        }
      }
      float4 ov;
      ov.x = fmaxf(fmaxf(acc[0], acc[1]), 0.f);
      ov.y = fmaxf(fmaxf(acc[2], acc[3]), 0.f);
      ov.z = fmaxf(fmaxf(acc[4], acc[5]), 0.f);
      ov.w = fmaxf(fmaxf(acc[6], acc[7]), 0.f);
      *(float4*)(H3 + (size_t)(n0 + im) * 512 + (size_t)(ch * 64 + oc) * 4) = ov;
    }
  }
}

// ================= GP projection: GP[n][0:32)=tanh(Wbn1.h), [32:96)=gc1w.h ==========
__global__ __launch_bounds__(256) void gp_kernel(
    const float* __restrict__ H3, const float* __restrict__ Wbn1,
    const float* __restrict__ gc1w, float* __restrict__ GP)
{
  __shared__ float sH[32 * 65];   // pitch 65
  __shared__ float sW[96 * 65];
  const int tid = threadIdx.x;
  const int n0 = blockIdx.x * 32;
  const int im = tid >> 3;
  const int oq = tid & 7;

  float acc[12];
#pragma unroll
  for (int j = 0; j < 12; ++j) acc[j] = 0.f;

#pragma unroll 1
  for (int c8 = 0; c8 < 8; ++c8) {
    const int d0 = c8 * 64;
    __syncthreads();
    for (int i = tid; i < 2048; i += 256) {
      const int r = i >> 6, cc = i & 63;
      sH[r * 65 + cc] = H3[(size_t)(n0 + r) * 512 + d0 + cc];   // coalesced
    }
    for (int i = tid; i < 6144; i += 256) {
      const int o = i >> 6, cc = i & 63;
      sW[o * 65 + cc] = (o < 32) ? Wbn1[o * 512 + d0 + cc]
                                 : gc1w[(o - 32) * 512 + d0 + cc];
    }
    __syncthreads();
#pragma unroll 4
    for (int d = 0; d < 64; ++d) {
      const float h = sH[im * 65 + d];     // 8 addrs/wave: conflict-free
#pragma unroll
      for (int j = 0; j < 12; ++j)
        acc[j] += h * sW[(oq * 12 + j) * 65 + d];   // 8 distinct banks
    }
  }
  float* gpo = GP + (size_t)(n0 + im) * 96;
#pragma unroll
  for (int j = 0; j < 12; ++j) {
    const int o = oq * 12 + j;
    gpo[o] = (o < 32) ? (1.f - 2.f / (__expf(2.f * acc[j]) + 1.f)) : acc[j];
  }
}

// ================= SOGC layer 1 (consumes GP) =================
__global__ __launch_bounds__(256) void sogc1_kernel(
    const float* __restrict__ GP, const float* __restrict__ gcb,
    float* __restrict__ Hout)
{
  __shared__ float sG[62 * 33];
  __shared__ float sP[62 * 64];
  __shared__ float stv[620];
  __shared__ int   sti[620];
  const int b = blockIdx.x, tid = threadIdx.x;
  const int lane = tid & 63, wave = tid >> 6;

  const float* gp = GP + (size_t)b * 62 * 96;
  for (int i = tid; i < 62 * 96; i += 256) {
    const int e = i / 96, q = i - e * 96;
    const float v = gp[i];
    if (q < 32) sG[e * 33 + q] = v; else sP[e * 64 + (q - 32)] = v;
  }
  __syncthreads();

  for (int e = wave; e < E_NODES; e += 4) {
    float sc = -1e30f;
    if (lane < E_NODES) {
      float s = 0.f;
#pragma unroll
      for (int k = 0; k < 32; ++k) s += sG[e * 33 + k] * sG[lane * 33 + k];
      sc = s;
    }
    float mx = sc;
#pragma unroll
    for (int off = 32; off; off >>= 1) mx = fmaxf(mx, __shfl_xor(mx, off));
    float p = (lane < E_NODES) ? __expf(sc - mx) : 0.f;
    float sum = p;
#pragma unroll
    for (int off = 32; off; off >>= 1) sum += __shfl_xor(sum, off);
    p = p / sum;
    float v = (lane < E_NODES) ? p : -1.f;
#pragma unroll 1
    for (int it = 0; it < TOPK; ++it) {
      float bv = v; int bi = lane;
#pragma unroll
      for (int off = 32; off; off >>= 1) {
        const float ov = __shfl_xor(bv, off);
        const int   oi = __shfl_xor(bi, off);
        if (ov > bv || (ov == bv && oi < bi)) { bv = ov; bi = oi; }  // lax.top_k tie-break
      }
      if (lane == 0) { stv[e * 10 + it] = bv; sti[e * 10 + it] = bi; }
      if (lane == bi) v = -1.f;
    }
  }
  __syncthreads();

  for (int e = wave; e < E_NODES; e += 4) {
    float acc = gcb[lane];
#pragma unroll
    for (int j = 0; j < TOPK; ++j)
      acc += stv[e * 10 + j] * sP[sti[e * 10 + j] * 64 + lane];
    Hout[((size_t)b * E_NODES + e) * 64 + lane] = fmaxf(acc, 0.f);
  }
}

// ================= SOGC layers 2/3 (DIN=64), cls fused into layer 3 =================
template <bool CLS>
__global__ __launch_bounds__(256) void sogc64_kernel(
    const float* __restrict__ Hin, const float* __restrict__ Wbn,
    const float* __restrict__ gcw, const float* __restrict__ gcb,
    const float* __restrict__ cw, const float* __restrict__ cb,
    float* __restrict__ outbuf)   // Hout (b,62,64) or logits (b,4)
{
  extern __shared__ float sm[];
  float* sH  = sm;                 // 62*65 = 4030
  float* sWt = sm + 4030;          // 64*97 = 6208
  float* sG  = sm + 10238;         // 62*33 = 2046
  float* sP  = sm + 12284;         // 62*64 = 3968
  float* stv = sm + 16252;         // 620
  int*   sti = (int*)(sm + 16872); // 620
  float* sred = sm + 17492;        // 16

  const int b = blockIdx.x, tid = threadIdx.x;
  const int lane = tid & 63, wave = tid >> 6;

  const float* Hb = Hin + (size_t)b * 62 * 64;
  for (int i = tid; i < 62 * 64; i += 256)
    sH[(i >> 6) * 65 + (i & 63)] = Hb[i];
  for (int i = tid; i < 64 * 64; i += 256)        // gcw (o,d) -> sWt[d][o]
    sWt[(i & 63) * 97 + (i >> 6)] = gcw[i];
  for (int i = tid; i < 32 * 64; i += 256)        // Wbn (k,d) -> sWt[d][64+k]
    sWt[(i & 63) * 97 + 64 + (i >> 6)] = Wbn[i];
  __syncthreads();

  for (int e = wave; e < E_NODES; e += 4) {
    const float* hrow = sH + e * 65;
    const float* wp = sWt + lane;
    const float* wg = sWt + 64 + (lane & 31);
    float accp = 0.f, accg = 0.f;
#pragma unroll 8
    for (int d = 0; d < 64; ++d) {
      const float h = hrow[d];
      accp += h * wp[d * 97];
      accg += h * wg[d * 97];
    }
    sP[e * 64 + lane] = accp;
    if (lane < 32) sG[e * 33 + lane] = 1.f - 2.f / (__expf(2.f * accg) + 1.f);
  }
  __syncthreads();

  for (int e = wave; e < E_NODES; e += 4) {
    float sc = -1e30f;
    if (lane < E_NODES) {
      float s = 0.f;
#pragma unroll
      for (int k = 0; k < 32; ++k) s += sG[e * 33 + k] * sG[lane * 33 + k];
      sc = s;
    }
    float mx = sc;
#pragma unroll
    for (int off = 32; off; off >>= 1) mx = fmaxf(mx, __shfl_xor(mx, off));
    float p = (lane < E_NODES) ? __expf(sc - mx) : 0.f;
    float sum = p;
#pragma unroll
    for (int off = 32; off; off >>= 1) sum += __shfl_xor(sum, off);
    p = p / sum;
    float v = (lane < E_NODES) ? p : -1.f;
#pragma unroll 1
    for (int it = 0; it < TOPK; ++it) {
      float bv = v; int bi = lane;
#pragma unroll
      for (int off = 32; off; off >>= 1) {
        const float ov = __shfl_xor(bv, off);
        const int   oi = __shfl_xor(bi, off);
        if (ov > bv || (ov == bv && oi < bi)) { bv = ov; bi = oi; }
      }
      if (lane == 0) { stv[e * 10 + it] = bv; sti[e * 10 + it] = bi; }
      if (lane == bi) v = -1.f;
    }
  }
  __syncthreads();

  float accn[4] = {0.f, 0.f, 0.f, 0.f};
  for (int e = wave; e < E_NODES; e += 4) {
    float acc = gcb[lane];
#pragma unroll
    for (int j = 0; j < TOPK; ++j)
      acc += stv[e * 10 + j] * sP[sti[e * 10 + j] * 64 + lane];
    acc = fmaxf(acc, 0.f);
    if (CLS) {
#pragma unroll
      for (int n = 0; n < 4; ++n)
        accn[n] += acc * cw[n * 3968 + e * 64 + lane];
    } else {
      outbuf[((size_t)b * E_NODES + e) * 64 + lane] = acc;
    }
  }
  if (CLS) {
#pragma unroll
    for (int n = 0; n < 4; ++n) {
      float s = accn[n];
#pragma unroll
      for (int off = 32; off; off >>= 1) s += __shfl_xor(s, off);
      if (lane == 0) sred[wave * 4 + n] = s;
    }
    __syncthreads();
    if (tid < 4)
      outbuf[b * 4 + tid] = cb[tid] + sred[tid] + sred[4 + tid] + sred[8 + tid] + sred[12 + tid];
  }
}

// ================= launch =================
extern "C" void kernel_launch(void* const* d_in, const int* in_sizes, int n_in,
                              void* d_out, int out_size, void* d_ws, size_t ws_size,
                              hipStream_t stream) {
  const float* x    = (const float*)d_in[0];
  const float* c1w  = (const float*)d_in[1];
  const float* c1b  = (const float*)d_in[2];
  const float* c2w  = (const float*)d_in[3];
  const float* c2b  = (const float*)d_in[4];
  const float* c3w  = (const float*)d_in[5];
  const float* c3b  = (const float*)d_in[6];
  const float* Wbn1 = (const float*)d_in[7];
  const float* gc1w = (const float*)d_in[8];
  const float* gc1b = (const float*)d_in[9];
  const float* Wbn2 = (const float*)d_in[10];
  const float* gc2w = (const float*)d_in[11];
  const float* gc2b = (const float*)d_in[12];
  const float* Wbn3 = (const float*)d_in[13];
  const float* gc3w = (const float*)d_in[14];
  const float* gc3b = (const float*)d_in[15];
  const float* clsw = (const float*)d_in[16];
  const float* clsb = (const float*)d_in[17];
  float* out = (float*)d_out;

  float* wsf = (float*)d_ws;
  float* H3  = wsf;                         // 31744*512 floats
  float* GP  = wsf + (size_t)16252928;      // 31744*96
  float* Hs1 = GP + (size_t)3047424;        // 512*62*64
  float* Hs2 = Hs1 + (size_t)2031616;

  const int SOGC64_BYTES = 17508 * 4;       // 70,032 B dynamic LDS

  (void)hipFuncSetAttribute((const void*)sogc64_kernel<false>,
                            hipFuncAttributeMaxDynamicSharedMemorySize, SOGC64_BYTES);
  (void)hipFuncSetAttribute((const void*)sogc64_kernel<true>,
                            hipFuncAttributeMaxDynamicSharedMemorySize, SOGC64_BYTES);

  conv_chain_kernel<<<7936, 256, 0, stream>>>(x, c1w, c1b, c2w, c2b, c3w, c3b, H3);
  gp_kernel<<<992, 256, 0, stream>>>(H3, Wbn1, gc1w, GP);
  sogc1_kernel<<<512, 256, 0, stream>>>(GP, gc1b, Hs1);
  sogc64_kernel<false><<<512, 256, SOGC64_BYTES, stream>>>(
      Hs1, Wbn2, gc2w, gc2b, nullptr, nullptr, Hs2);
  sogc64_kernel<true><<<512, 256, SOGC64_BYTES, stream>>>(
      Hs2, Wbn3, gc3w, gc3b, clsw, clsb, out);
}

// Round 6
// 1308.498 us; speedup vs baseline: 2.9917x; 1.1596x over previous
//
#include <hip/hip_runtime.h>

#define E_NODES 62
#define TOPK 10
// conv geometry: (5,64) -> c1 5x5 -> (1,60) -> pool -> 30
//                -> c2 1x5 (64ch) -> 26 -> pool -> 13
//                -> c3 1x5 (128ch) -> 9 -> pool -> 4 (pos 8 unused)

// ---- weight transpose: w2 (64,160)->w2t(160,64); w3 (128,320)->w3t(320,128)
__global__ __launch_bounds__(256) void wt_kernel(
    const float* __restrict__ w2, const float* __restrict__ w3,
    float* __restrict__ w2t, float* __restrict__ w3t)
{
  const int j = blockIdx.x * 256 + threadIdx.x;
  if (j < 10240) {
    const int r = j >> 6, o = j & 63;
    w2t[j] = w2[o * 160 + r];
  } else {
    const int k = j - 10240;               // < 40960
    const int r = k >> 7, o = k & 127;
    w3t[k] = w3[o * 320 + r];
  }
}

// async global->LDS linear copy (n multiple of 256); dest pattern is the
// HW-required wave-uniform base + lane*4.
__device__ __forceinline__ void stage_async(const float* __restrict__ g,
                                            float* l, int n, int tid) {
  for (int i = tid; i < n; i += 256)
    __builtin_amdgcn_global_load_lds(
        (const __attribute__((address_space(1))) void*)(g + i),
        (__attribute__((address_space(3))) void*)(l + i), 4, 0, 0);
}

// ================= fused conv chain =================
// 256 threads / block, 4 images (wave = image). Writes H3 (31744,512).
// LDS floats: h1[4][32][32]@0 | h2[4][64][16]@4096 | wzone@8192 (5120:
//   conv1 w+b @8192, img @9024 -- both dead before first w-chunk stage)
//   | b2/b3 @13312 (192). Total 13504 fl = 54016 B -> 3 blocks/CU.
// __launch_bounds__(256,3): unified VGPR file 512/wave -> cap ~170;
// live sets kept ~50-70 (round-4 lesson: exceeding cap => GBs of spill).

__global__ __launch_bounds__(256, 3) void conv_chain_kernel(
    const float* __restrict__ x,
    const float* __restrict__ w1, const float* __restrict__ b1,
    const float* __restrict__ w2t, const float* __restrict__ b2,
    const float* __restrict__ w3t, const float* __restrict__ b3,
    float* __restrict__ H3)
{
  __shared__ float sm[13504];
  float* s_h1  = sm;            // 4*32*32 (pitch 32)
  float* s_h2  = sm + 4096;     // 4*64*16 (pitch 16)
  float* s_w   = sm + 8192;     // 5120 chunk zone
  float* s_w1  = sm + 8192;     // conv1 w(800)+b(32) inside zone
  float* s_img = sm + 9024;     // 1280 inside zone
  float* s_b   = sm + 13312;    // b2[0:64) b3[64:192)

  const int tid = threadIdx.x;
  const int n0 = blockIdx.x * 4;
  const int im = tid >> 6;
  const int lane = tid & 63;

  stage_async(x + (size_t)n0 * 320, s_img, 1280, tid);
  for (int i = tid; i < 832; i += 256) s_w1[i] = (i < 800) ? w1[i] : b1[i - 800];
  for (int i = tid; i < 192; i += 256) s_b[i] = (i < 64) ? b2[i] : b3[i - 64];
  __syncthreads();

  // ---- conv1 + relu + pool. lane = (half, tp): stride-1 writes (no conflict)
  {
    const int tp = lane & 31;        // pooled position, 0..29 used
    const int half = lane >> 5;      // output-channel half
    if (tp < 30) {
      const float* ib = s_img + im * 320;
      const int t0 = 2 * tp;
      float r[5][6];
#pragma unroll
      for (int kr = 0; kr < 5; ++kr)
#pragma unroll
        for (int c = 0; c < 6; ++c) r[kr][c] = ib[kr * 64 + t0 + c];
#pragma unroll 4
      for (int oi = 0; oi < 16; ++oi) {
        const int o = half * 16 + oi;
        const float* w = s_w1 + o * 25;       // 2-address broadcast reads
        float s0 = s_w1[800 + o], s1 = s0;
#pragma unroll
        for (int kr = 0; kr < 5; ++kr) {
#pragma unroll
          for (int k = 0; k < 5; ++k) {       // pure v_fmac form
            const float wv = w[kr * 5 + k];
            s0 += r[kr][k] * wv;
            s1 += r[kr][k + 1] * wv;
          }
        }
        s_h1[im * 1024 + o * 32 + tp] = fmaxf(fmaxf(s0, s1), 0.f);
      }
    }
  }

  // ---- conv2 + relu + pool: thread = (im, o). T-TILED (7+6) for reg pressure.
  // weights: w2t rows cik = ci*5+k, cols o. chunk c = rows [c*40,c*40+40).
  {
    const int o = lane;
    const float bia = s_b[o];

    // tile 0: pooled t = 0..6 (inputs 0..17)
    {
      float acc0[7], acc1[7];
#pragma unroll
      for (int t = 0; t < 7; ++t) { acc0[t] = bia; acc1[t] = bia; }
#pragma unroll 1
      for (int c = 0; c < 4; ++c) {
        __syncthreads();
        stage_async(w2t + c * 2560, s_w, 2560, tid);   // linear, async
        __syncthreads();
#pragma unroll 4
        for (int cl = 0; cl < 8; ++cl) {
          const float* hr = s_h1 + im * 1024 + (c * 8 + cl) * 32;  // broadcast
          float r[18];
#pragma unroll
          for (int q = 0; q < 4; ++q) {
            const float4 v = *(const float4*)(hr + q * 4);
            r[q * 4] = v.x; r[q * 4 + 1] = v.y; r[q * 4 + 2] = v.z; r[q * 4 + 3] = v.w;
          }
          { const float2 v = *(const float2*)(hr + 16); r[16] = v.x; r[17] = v.y; }
          const float* wb = s_w + cl * 320 + o;        // (cl*5+k)*64+o, imm offsets
#pragma unroll
          for (int k = 0; k < 5; ++k) {
            const float wv = wb[k * 64];
#pragma unroll
            for (int t = 0; t < 7; ++t) {              // pure v_fmac
              acc0[t] += r[2 * t + k] * wv;
              acc1[t] += r[2 * t + 1 + k] * wv;
            }
          }
        }
      }
#pragma unroll
      for (int t = 0; t < 7; ++t)
        s_h2[im * 1024 + o * 16 + t] = fmaxf(fmaxf(acc0[t], acc1[t]), 0.f);
    }

    // tile 1: pooled t = 7..12 (inputs 14..29; r[j] = input[12+j])
    {
      float acc0[6], acc1[6];
#pragma unroll
      for (int t = 0; t < 6; ++t) { acc0[t] = bia; acc1[t] = bia; }
#pragma unroll 1
      for (int c = 0; c < 4; ++c) {
        __syncthreads();
        stage_async(w2t + c * 2560, s_w, 2560, tid);
        __syncthreads();
#pragma unroll 4
        for (int cl = 0; cl < 8; ++cl) {
          const float* hr = s_h1 + im * 1024 + (c * 8 + cl) * 32;
          float r[18];
#pragma unroll
          for (int q = 0; q < 4; ++q) {
            const float4 v = *(const float4*)(hr + 12 + q * 4);
            r[q * 4] = v.x; r[q * 4 + 1] = v.y; r[q * 4 + 2] = v.z; r[q * 4 + 3] = v.w;
          }
          { const float2 v = *(const float2*)(hr + 28); r[16] = v.x; r[17] = v.y; }
          const float* wb = s_w + cl * 320 + o;
#pragma unroll
          for (int k = 0; k < 5; ++k) {
            const float wv = wb[k * 64];
#pragma unroll
            for (int t = 0; t < 6; ++t) {
              const int t0 = 2 * t + 2;                // input[2(t+7)] local
              acc0[t] += r[t0 + k] * wv;
              acc1[t] += r[t0 + 1 + k] * wv;
            }
          }
        }
      }
#pragma unroll
      for (int t = 0; t < 6; ++t)
        s_h2[im * 1024 + o * 16 + 7 + t] = fmaxf(fmaxf(acc0[t], acc1[t]), 0.f);
    }
  }

  // ---- conv3 + relu + pool -> H3. 2-oc register tile (oc = lane, lane+64):
  // halves h2 reads/FLOP and staging rounds (chunk = 40 rows x 128 = 5120).
  {
    const int oc = lane;
    float acc[2][8];
#pragma unroll
    for (int t = 0; t < 8; ++t) {
      acc[0][t] = s_b[64 + oc];
      acc[1][t] = s_b[128 + oc];
    }
#pragma unroll 1
    for (int c = 0; c < 8; ++c) {
      __syncthreads();
      stage_async(w3t + c * 5120, s_w, 5120, tid);     // linear, async
      __syncthreads();
#pragma unroll 2
      for (int cl = 0; cl < 8; ++cl) {
        const float* hr = s_h2 + im * 1024 + (c * 8 + cl) * 16;  // broadcast
        float r[12];
#pragma unroll
        for (int q = 0; q < 3; ++q) {
          const float4 v = *(const float4*)(hr + q * 4);
          r[q * 4] = v.x; r[q * 4 + 1] = v.y; r[q * 4 + 2] = v.z; r[q * 4 + 3] = v.w;
        }
        const float* wb = s_w + cl * 640 + oc;         // (cl*5+k)*128+oc
#pragma unroll
        for (int k = 0; k < 5; ++k) {
          const float wv0 = wb[k * 128];
          const float wv1 = wb[k * 128 + 64];
#pragma unroll
          for (int t = 0; t < 8; ++t) {                // pure v_fmac
            acc[0][t] += r[t + k] * wv0;
            acc[1][t] += r[t + k] * wv1;
          }
        }
      }
    }
    float* hout = H3 + (size_t)(n0 + im) * 512;
    float4 ov;
    ov.x = fmaxf(fmaxf(acc[0][0], acc[0][1]), 0.f);
    ov.y = fmaxf(fmaxf(acc[0][2], acc[0][3]), 0.f);
    ov.z = fmaxf(fmaxf(acc[0][4], acc[0][5]), 0.f);
    ov.w = fmaxf(fmaxf(acc[0][6], acc[0][7]), 0.f);
    *(float4*)(hout + oc * 4) = ov;
    ov.x = fmaxf(fmaxf(acc[1][0], acc[1][1]), 0.f);
    ov.y = fmaxf(fmaxf(acc[1][2], acc[1][3]), 0.f);
    ov.z = fmaxf(fmaxf(acc[1][4], acc[1][5]), 0.f);
    ov.w = fmaxf(fmaxf(acc[1][6], acc[1][7]), 0.f);
    *(float4*)(hout + (64 + oc) * 4) = ov;
  }
}

// ================= GP projection: GP[n][0:32)=tanh(Wbn1.h), [32:96)=gc1w.h ==========
__global__ __launch_bounds__(256) void gp_kernel(
    const float* __restrict__ H3, const float* __restrict__ Wbn1,
    const float* __restrict__ gc1w, float* __restrict__ GP)
{
  __shared__ float sH[32 * 65];   // pitch 65
  __shared__ float sW[96 * 65];
  const int tid = threadIdx.x;
  const int n0 = blockIdx.x * 32;
  const int im = tid >> 3;
  const int oq = tid & 7;

  float acc[12];
#pragma unroll
  for (int j = 0; j < 12; ++j) acc[j] = 0.f;

#pragma unroll 1
  for (int c8 = 0; c8 < 8; ++c8) {
    const int d0 = c8 * 64;
    __syncthreads();
    for (int i = tid; i < 2048; i += 256) {
      const int r = i >> 6, cc = i & 63;
      sH[r * 65 + cc] = H3[(size_t)(n0 + r) * 512 + d0 + cc];   // coalesced
    }
    for (int i = tid; i < 6144; i += 256) {
      const int o = i >> 6, cc = i & 63;
      sW[o * 65 + cc] = (o < 32) ? Wbn1[o * 512 + d0 + cc]
                                 : gc1w[(o - 32) * 512 + d0 + cc];
    }
    __syncthreads();
#pragma unroll 4
    for (int d = 0; d < 64; ++d) {
      const float h = sH[im * 65 + d];     // 8 addrs/wave: conflict-free
#pragma unroll
      for (int j = 0; j < 12; ++j)
        acc[j] += h * sW[(oq * 12 + j) * 65 + d];
    }
  }
  float* gpo = GP + (size_t)(n0 + im) * 96;
#pragma unroll
  for (int j = 0; j < 12; ++j) {
    const int o = oq * 12 + j;
    gpo[o] = (o < 32) ? (1.f - 2.f / (__expf(2.f * acc[j]) + 1.f)) : acc[j];
  }
}

// ================= SOGC layer 1 (consumes GP) =================
__global__ __launch_bounds__(256) void sogc1_kernel(
    const float* __restrict__ GP, const float* __restrict__ gcb,
    float* __restrict__ Hout)
{
  __shared__ float sG[62 * 33];
  __shared__ float sP[62 * 64];
  __shared__ float stv[620];
  __shared__ int   sti[620];
  const int b = blockIdx.x, tid = threadIdx.x;
  const int lane = tid & 63, wave = tid >> 6;

  const float* gp = GP + (size_t)b * 62 * 96;
  for (int i = tid; i < 62 * 96; i += 256) {
    const int e = i / 96, q = i - e * 96;
    const float v = gp[i];
    if (q < 32) sG[e * 33 + q] = v; else sP[e * 64 + (q - 32)] = v;
  }
  __syncthreads();

  for (int e = wave; e < E_NODES; e += 4) {
    float sc = -1e30f;
    if (lane < E_NODES) {
      float s = 0.f;
#pragma unroll
      for (int k = 0; k < 32; ++k) s += sG[e * 33 + k] * sG[lane * 33 + k];
      sc = s;
    }
    float mx = sc;
#pragma unroll
    for (int off = 32; off; off >>= 1) mx = fmaxf(mx, __shfl_xor(mx, off));
    float p = (lane < E_NODES) ? __expf(sc - mx) : 0.f;
    float sum = p;
#pragma unroll
    for (int off = 32; off; off >>= 1) sum += __shfl_xor(sum, off);
    p = p / sum;
    float v = (lane < E_NODES) ? p : -1.f;
#pragma unroll 1
    for (int it = 0; it < TOPK; ++it) {
      float bv = v; int bi = lane;
#pragma unroll
      for (int off = 32; off; off >>= 1) {
        const float ov = __shfl_xor(bv, off);
        const int   oi = __shfl_xor(bi, off);
        if (ov > bv || (ov == bv && oi < bi)) { bv = ov; bi = oi; }  // lax.top_k tie-break
      }
      if (lane == 0) { stv[e * 10 + it] = bv; sti[e * 10 + it] = bi; }
      if (lane == bi) v = -1.f;
    }
  }
  __syncthreads();

  for (int e = wave; e < E_NODES; e += 4) {
    float acc = gcb[lane];
#pragma unroll
    for (int j = 0; j < TOPK; ++j)
      acc += stv[e * 10 + j] * sP[sti[e * 10 + j] * 64 + lane];
    Hout[((size_t)b * E_NODES + e) * 64 + lane] = fmaxf(acc, 0.f);
  }
}

// ================= SOGC layers 2/3 (DIN=64), cls fused into layer 3 =================
template <bool CLS>
__global__ __launch_bounds__(256) void sogc64_kernel(
    const float* __restrict__ Hin, const float* __restrict__ Wbn,
    const float* __restrict__ gcw, const float* __restrict__ gcb,
    const float* __restrict__ cw, const float* __restrict__ cb,
    float* __restrict__ outbuf)   // Hout (b,62,64) or logits (b,4)
{
  extern __shared__ float sm[];
  float* sH  = sm;                 // 62*65 = 4030
  float* sWt = sm + 4030;          // 64*97 = 6208
  float* sG  = sm + 10238;         // 62*33 = 2046
  float* sP  = sm + 12284;         // 62*64 = 3968
  float* stv = sm + 16252;         // 620
  int*   sti = (int*)(sm + 16872); // 620
  float* sred = sm + 17492;        // 16

  const int b = blockIdx.x, tid = threadIdx.x;
  const int lane = tid & 63, wave = tid >> 6;

  const float* Hb = Hin + (size_t)b * 62 * 64;
  for (int i = tid; i < 62 * 64; i += 256)
    sH[(i >> 6) * 65 + (i & 63)] = Hb[i];
  for (int i = tid; i < 64 * 64; i += 256)        // gcw (o,d) -> sWt[d][o]
    sWt[(i & 63) * 97 + (i >> 6)] = gcw[i];
  for (int i = tid; i < 32 * 64; i += 256)        // Wbn (k,d) -> sWt[d][64+k]
    sWt[(i & 63) * 97 + 64 + (i >> 6)] = Wbn[i];
  __syncthreads();

  for (int e = wave; e < E_NODES; e += 4) {
    const float* hrow = sH + e * 65;
    const float* wp = sWt + lane;
    const float* wg = sWt + 64 + (lane & 31);
    float accp = 0.f, accg = 0.f;
#pragma unroll 8
    for (int d = 0; d < 64; ++d) {
      const float h = hrow[d];
      accp += h * wp[d * 97];
      accg += h * wg[d * 97];
    }
    sP[e * 64 + lane] = accp;
    if (lane < 32) sG[e * 33 + lane] = 1.f - 2.f / (__expf(2.f * accg) + 1.f);
  }
  __syncthreads();

  for (int e = wave; e < E_NODES; e += 4) {
    float sc = -1e30f;
    if (lane < E_NODES) {
      float s = 0.f;
#pragma unroll
      for (int k = 0; k < 32; ++k) s += sG[e * 33 + k] * sG[lane * 33 + k];
      sc = s;
    }
    float mx = sc;
#pragma unroll
    for (int off = 32; off; off >>= 1) mx = fmaxf(mx, __shfl_xor(mx, off));
    float p = (lane < E_NODES) ? __expf(sc - mx) : 0.f;
    float sum = p;
#pragma unroll
    for (int off = 32; off; off >>= 1) sum += __shfl_xor(sum, off);
    p = p / sum;
    float v = (lane < E_NODES) ? p : -1.f;
#pragma unroll 1
    for (int it = 0; it < TOPK; ++it) {
      float bv = v; int bi = lane;
#pragma unroll
      for (int off = 32; off; off >>= 1) {
        const float ov = __shfl_xor(bv, off);
        const int   oi = __shfl_xor(bi, off);
        if (ov > bv || (ov == bv && oi < bi)) { bv = ov; bi = oi; }
      }
      if (lane == 0) { stv[e * 10 + it] = bv; sti[e * 10 + it] = bi; }
      if (lane == bi) v = -1.f;
    }
  }
  __syncthreads();

  float accn[4] = {0.f, 0.f, 0.f, 0.f};
  for (int e = wave; e < E_NODES; e += 4) {
    float acc = gcb[lane];
#pragma unroll
    for (int j = 0; j < TOPK; ++j)
      acc += stv[e * 10 + j] * sP[sti[e * 10 + j] * 64 + lane];
    acc = fmaxf(acc, 0.f);
    if (CLS) {
#pragma unroll
      for (int n = 0; n < 4; ++n)
        accn[n] += acc * cw[n * 3968 + e * 64 + lane];
    } else {
      outbuf[((size_t)b * E_NODES + e) * 64 + lane] = acc;
    }
  }
  if (CLS) {
#pragma unroll
    for (int n = 0; n < 4; ++n) {
      float s = accn[n];
#pragma unroll
      for (int off = 32; off; off >>= 1) s += __shfl_xor(s, off);
      if (lane == 0) sred[wave * 4 + n] = s;
    }
    __syncthreads();
    if (tid < 4)
      outbuf[b * 4 + tid] = cb[tid] + sred[tid] + sred[4 + tid] + sred[8 + tid] + sred[12 + tid];
  }
}

// ================= launch =================
extern "C" void kernel_launch(void* const* d_in, const int* in_sizes, int n_in,
                              void* d_out, int out_size, void* d_ws, size_t ws_size,
                              hipStream_t stream) {
  const float* x    = (const float*)d_in[0];
  const float* c1w  = (const float*)d_in[1];
  const float* c1b  = (const float*)d_in[2];
  const float* c2w  = (const float*)d_in[3];
  const float* c2b  = (const float*)d_in[4];
  const float* c3w  = (const float*)d_in[5];
  const float* c3b  = (const float*)d_in[6];
  const float* Wbn1 = (const float*)d_in[7];
  const float* gc1w = (const float*)d_in[8];
  const float* gc1b = (const float*)d_in[9];
  const float* Wbn2 = (const float*)d_in[10];
  const float* gc2w = (const float*)d_in[11];
  const float* gc2b = (const float*)d_in[12];
  const float* Wbn3 = (const float*)d_in[13];
  const float* gc3w = (const float*)d_in[14];
  const float* gc3b = (const float*)d_in[15];
  const float* clsw = (const float*)d_in[16];
  const float* clsb = (const float*)d_in[17];
  float* out = (float*)d_out;

  float* wsf = (float*)d_ws;
  float* W2T = wsf;                         // 10240
  float* W3T = wsf + 10240;                 // 40960
  float* H3  = wsf + 51200;                 // 31744*512 = 16,252,928
  float* GP  = H3 + (size_t)16252928;       // 31744*96
  float* Hs1 = GP + (size_t)3047424;        // 512*62*64
  float* Hs2 = Hs1 + (size_t)2031616;       // total ~93.2 MB

  const int SOGC64_BYTES = 17508 * 4;       // 70,032 B dynamic LDS

  (void)hipFuncSetAttribute((const void*)sogc64_kernel<false>,
                            hipFuncAttributeMaxDynamicSharedMemorySize, SOGC64_BYTES);
  (void)hipFuncSetAttribute((const void*)sogc64_kernel<true>,
                            hipFuncAttributeMaxDynamicSharedMemorySize, SOGC64_BYTES);

  wt_kernel<<<200, 256, 0, stream>>>(c2w, c3w, W2T, W3T);
  conv_chain_kernel<<<7936, 256, 0, stream>>>(x, c1w, c1b, W2T, c2b, W3T, c3b, H3);
  gp_kernel<<<992, 256, 0, stream>>>(H3, Wbn1, gc1w, GP);
  sogc1_kernel<<<512, 256, 0, stream>>>(GP, gc1b, Hs1);
  sogc64_kernel<false><<<512, 256, SOGC64_BYTES, stream>>>(
      Hs1, Wbn2, gc2w, gc2b, nullptr, nullptr, Hs2);
  sogc64_kernel<true><<<512, 256, SOGC64_BYTES, stream>>>(
      Hs2, Wbn3, gc3w, gc3b, clsw, clsb, out);
}

// Round 7
// 1178.461 us; speedup vs baseline: 3.3218x; 1.1103x over previous
//
#include <hip/hip_runtime.h>

#define E_NODES 62
#define TOPK 10
// conv geometry: (5,64) -> c1 5x5 -> (1,60) -> pool -> 30
//                -> c2 1x5 (64ch) -> 26 -> pool -> 13
//                -> c3 1x5 (128ch) -> 9 -> pool -> 4 (pos 8 unused)

// ---- weight transpose: w2 (64,160)->w2t(160,64); w3 (128,320)->w3t(320,128)
__global__ __launch_bounds__(256) void wt_kernel(
    const float* __restrict__ w2, const float* __restrict__ w3,
    float* __restrict__ w2t, float* __restrict__ w3t)
{
  const int j = blockIdx.x * 256 + threadIdx.x;
  if (j < 10240) {
    const int r = j >> 6, o = j & 63;
    w2t[j] = w2[o * 160 + r];
  } else {
    const int k = j - 10240;               // < 40960
    const int r = k >> 7, o = k & 127;
    w3t[k] = w3[o * 320 + r];
  }
}

// async global->LDS linear copy (n multiple of 256); dest = wave-uniform
// base + lane*4 (the HW-required pattern).
__device__ __forceinline__ void stage_async(const float* __restrict__ g,
                                            float* l, int n, int tid) {
  for (int i = tid; i < n; i += 256)
    __builtin_amdgcn_global_load_lds(
        (const __attribute__((address_space(1))) void*)(g + i),
        (__attribute__((address_space(3))) void*)(l + i), 4, 0, 0);
}

// ================= fused conv chain =================
// 256 threads / block, 4 images (wave = image). Writes H3 (31744,512).
// LDS floats: h1[4][32][32]@0 | h2[4][64][16]@4096 | wA@8192(2560) wB@10752(2560)
//   conv1 w+b @8192 (832) + img @9024 (1280) alias wA (dead before wA staged).
// Total 13312 fl = 53248 B -> 3 blocks/CU (54016 B tipped to 2 in round 6).
// Double-buffered weight chunks: stage s+1 async into other buf, compute s,
// ONE barrier per chunk (its implicit vmcnt-drain lands after full compute).
// __launch_bounds__(256,3): unified file 512/wave -> cap ~170; live sets ~60.

__global__ __launch_bounds__(256, 3) void conv_chain_kernel(
    const float* __restrict__ x,
    const float* __restrict__ w1, const float* __restrict__ b1,
    const float* __restrict__ w2t, const float* __restrict__ b2,
    const float* __restrict__ w3t, const float* __restrict__ b3,
    float* __restrict__ H3)
{
  __shared__ float sm[13312];
  float* s_h1  = sm;            // 4*32*32 (pitch 32)
  float* s_h2  = sm + 4096;     // 4*64*16 (pitch 16)
  float* s_wa  = sm + 8192;     // 2560
  float* s_wb  = sm + 10752;    // 2560
  float* s_w1  = sm + 8192;     // conv1 w(800)+b(32), aliases wA
  float* s_img = sm + 9024;     // 1280, aliases wA

  const int tid = threadIdx.x;
  const int n0 = blockIdx.x * 4;
  const int im = tid >> 6;
  const int lane = tid & 63;

  stage_async(x + (size_t)n0 * 320, s_img, 1280, tid);
  for (int i = tid; i < 832; i += 256) s_w1[i] = (i < 800) ? w1[i] : b1[i - 800];
  __syncthreads();

  // stage conv2 chunk 0 -> wB during conv1 compute (wA still live for conv1)
  stage_async(w2t, s_wb, 2560, tid);

  // ---- conv1 + relu + pool. lane = (half, tp): stride-1 writes (no conflict)
  {
    const int tp = lane & 31;        // pooled position, 0..29 used
    const int half = lane >> 5;      // output-channel half
    if (tp < 30) {
      const float* ib = s_img + im * 320;
      const int t0 = 2 * tp;
      float r[5][6];
#pragma unroll
      for (int kr = 0; kr < 5; ++kr)
#pragma unroll
        for (int c = 0; c < 6; ++c) r[kr][c] = ib[kr * 64 + t0 + c];
#pragma unroll 4
      for (int oi = 0; oi < 16; ++oi) {
        const int o = half * 16 + oi;
        const float* w = s_w1 + o * 25;       // 2-address broadcast reads
        float s0 = s_w1[800 + o], s1 = s0;
#pragma unroll
        for (int kr = 0; kr < 5; ++kr) {
#pragma unroll
          for (int k = 0; k < 5; ++k) {       // pure v_fmac form
            const float wv = w[kr * 5 + k];
            s0 += r[kr][k] * wv;
            s1 += r[kr][k + 1] * wv;
          }
        }
        s_h1[im * 1024 + o * 32 + tp] = fmaxf(fmaxf(s0, s1), 0.f);
      }
    }
  }
  __syncthreads();   // h1 ready; conv2 chunk0 staged (vmcnt drained)

  // ---- conv2 + relu + pool: thread = (im, o). T-TILED (7+6) for reg pressure.
  // stage sequence s=0..7: chunks 0,1,2,3,0,1,2,3; buf parity s&1 (0->B,1->A).
  {
    const int o = lane;
    const float bia = b2[o];

    // tile 0: pooled t = 0..6 (inputs 0..17); s = c
    {
      float acc0[7], acc1[7];
#pragma unroll
      for (int t = 0; t < 7; ++t) { acc0[t] = bia; acc1[t] = bia; }
#pragma unroll 1
      for (int c = 0; c < 4; ++c) {
        const float* rb = (c & 1) ? s_wa : s_wb;
        float*       nb = (c & 1) ? s_wb : s_wa;
        stage_async(w2t + ((c < 3) ? (c + 1) * 2560 : 0), nb, 2560, tid);
#pragma unroll 4
        for (int cl = 0; cl < 8; ++cl) {
          const float* hr = s_h1 + im * 1024 + (c * 8 + cl) * 32;  // broadcast
          float r[18];
#pragma unroll
          for (int q = 0; q < 4; ++q) {
            const float4 v = *(const float4*)(hr + q * 4);
            r[q * 4] = v.x; r[q * 4 + 1] = v.y; r[q * 4 + 2] = v.z; r[q * 4 + 3] = v.w;
          }
          { const float2 v = *(const float2*)(hr + 16); r[16] = v.x; r[17] = v.y; }
          const float* wb = rb + cl * 320 + o;         // (cl*5+k)*64+o, imm offsets
#pragma unroll
          for (int k = 0; k < 5; ++k) {
            const float wv = wb[k * 64];
#pragma unroll
            for (int t = 0; t < 7; ++t) {              // pure v_fmac
              acc0[t] += r[2 * t + k] * wv;
              acc1[t] += r[2 * t + 1 + k] * wv;
            }
          }
        }
        __syncthreads();    // next chunk staged + all reads of rb done
      }
#pragma unroll
      for (int t = 0; t < 7; ++t)
        s_h2[im * 1024 + o * 16 + t] = fmaxf(fmaxf(acc0[t], acc1[t]), 0.f);
    }

    // tile 1: pooled t = 7..12 (inputs 14..29; r[j] = input[12+j]); s = 4+c
    {
      float acc0[6], acc1[6];
#pragma unroll
      for (int t = 0; t < 6; ++t) { acc0[t] = bia; acc1[t] = bia; }
#pragma unroll 1
      for (int c = 0; c < 4; ++c) {
        const float* rb = (c & 1) ? s_wa : s_wb;
        float*       nb = (c & 1) ? s_wb : s_wa;
        // next: tile1 chunk c+1, else conv3 chunk 0
        stage_async((c < 3) ? (w2t + (c + 1) * 2560) : w3t, nb, 2560, tid);
#pragma unroll 4
        for (int cl = 0; cl < 8; ++cl) {
          const float* hr = s_h1 + im * 1024 + (c * 8 + cl) * 32;
          float r[18];
#pragma unroll
          for (int q = 0; q < 4; ++q) {
            const float4 v = *(const float4*)(hr + 12 + q * 4);
            r[q * 4] = v.x; r[q * 4 + 1] = v.y; r[q * 4 + 2] = v.z; r[q * 4 + 3] = v.w;
          }
          { const float2 v = *(const float2*)(hr + 28); r[16] = v.x; r[17] = v.y; }
          const float* wb = rb + cl * 320 + o;
#pragma unroll
          for (int k = 0; k < 5; ++k) {
            const float wv = wb[k * 64];
#pragma unroll
            for (int t = 0; t < 6; ++t) {
              const int t0 = 2 * t + 2;                // input[2(t+7)] local
              acc0[t] += r[t0 + k] * wv;
              acc1[t] += r[t0 + 1 + k] * wv;
            }
          }
        }
        __syncthreads();
      }
#pragma unroll
      for (int t = 0; t < 6; ++t)
        s_h2[im * 1024 + o * 16 + 7 + t] = fmaxf(fmaxf(acc0[t], acc1[t]), 0.f);
    }
  }

  // ---- conv3 + relu + pool -> H3. 2-oc register tile (oc = lane, lane+64).
  // 16 chunks of 4 ci (20 rows x 128 = 2560 fl); s = 8+k, parity k&1.
  {
    const int oc = lane;
    float acc[2][8];
#pragma unroll
    for (int t = 0; t < 8; ++t) {
      acc[0][t] = b3[oc];
      acc[1][t] = b3[64 + oc];
    }
#pragma unroll 1
    for (int k = 0; k < 16; ++k) {
      const float* rb = (k & 1) ? s_wa : s_wb;
      float*       nb = (k & 1) ? s_wb : s_wa;
      if (k < 15) stage_async(w3t + (k + 1) * 2560, nb, 2560, tid);
#pragma unroll 2
      for (int cl = 0; cl < 4; ++cl) {
        const float* hr = s_h2 + im * 1024 + (k * 4 + cl) * 16;  // broadcast
        float r[12];
#pragma unroll
        for (int q = 0; q < 3; ++q) {
          const float4 v = *(const float4*)(hr + q * 4);
          r[q * 4] = v.x; r[q * 4 + 1] = v.y; r[q * 4 + 2] = v.z; r[q * 4 + 3] = v.w;
        }
        const float* wb = rb + cl * 640 + oc;          // (cl*5+kk)*128+oc
#pragma unroll
        for (int kk = 0; kk < 5; ++kk) {
          const float wv0 = wb[kk * 128];
          const float wv1 = wb[kk * 128 + 64];
#pragma unroll
          for (int t = 0; t < 8; ++t) {                // pure v_fmac
            acc[0][t] += r[t + kk] * wv0;
            acc[1][t] += r[t + kk] * wv1;
          }
        }
      }
      __syncthreads();
    }
    float* hout = H3 + (size_t)(n0 + im) * 512;
    float4 ov;
    ov.x = fmaxf(fmaxf(acc[0][0], acc[0][1]), 0.f);
    ov.y = fmaxf(fmaxf(acc[0][2], acc[0][3]), 0.f);
    ov.z = fmaxf(fmaxf(acc[0][4], acc[0][5]), 0.f);
    ov.w = fmaxf(fmaxf(acc[0][6], acc[0][7]), 0.f);
    *(float4*)(hout + oc * 4) = ov;
    ov.x = fmaxf(fmaxf(acc[1][0], acc[1][1]), 0.f);
    ov.y = fmaxf(fmaxf(acc[1][2], acc[1][3]), 0.f);
    ov.z = fmaxf(fmaxf(acc[1][4], acc[1][5]), 0.f);
    ov.w = fmaxf(fmaxf(acc[1][6], acc[1][7]), 0.f);
    *(float4*)(hout + (64 + oc) * 4) = ov;
  }
}

// ================= GP projection: GP[n][0:32)=tanh(Wbn1.h), [32:96)=gc1w.h ==========
__global__ __launch_bounds__(256) void gp_kernel(
    const float* __restrict__ H3, const float* __restrict__ Wbn1,
    const float* __restrict__ gc1w, float* __restrict__ GP)
{
  __shared__ float sH[32 * 65];   // pitch 65
  __shared__ float sW[96 * 65];
  const int tid = threadIdx.x;
  const int n0 = blockIdx.x * 32;
  const int im = tid >> 3;
  const int oq = tid & 7;

  float acc[12];
#pragma unroll
  for (int j = 0; j < 12; ++j) acc[j] = 0.f;

#pragma unroll 1
  for (int c8 = 0; c8 < 8; ++c8) {
    const int d0 = c8 * 64;
    __syncthreads();
    for (int i = tid; i < 2048; i += 256) {
      const int r = i >> 6, cc = i & 63;
      sH[r * 65 + cc] = H3[(size_t)(n0 + r) * 512 + d0 + cc];   // coalesced
    }
    for (int i = tid; i < 6144; i += 256) {
      const int o = i >> 6, cc = i & 63;
      sW[o * 65 + cc] = (o < 32) ? Wbn1[o * 512 + d0 + cc]
                                 : gc1w[(o - 32) * 512 + d0 + cc];
    }
    __syncthreads();
#pragma unroll 4
    for (int d = 0; d < 64; ++d) {
      const float h = sH[im * 65 + d];     // 8 addrs/wave: conflict-free
#pragma unroll
      for (int j = 0; j < 12; ++j)
        acc[j] += h * sW[(oq * 12 + j) * 65 + d];
    }
  }
  float* gpo = GP + (size_t)(n0 + im) * 96;
#pragma unroll
  for (int j = 0; j < 12; ++j) {
    const int o = oq * 12 + j;
    gpo[o] = (o < 32) ? (1.f - 2.f / (__expf(2.f * acc[j]) + 1.f)) : acc[j];
  }
}

// ================= SOGC layer 1 (consumes GP) =================
__global__ __launch_bounds__(256) void sogc1_kernel(
    const float* __restrict__ GP, const float* __restrict__ gcb,
    float* __restrict__ Hout)
{
  __shared__ float sG[62 * 33];
  __shared__ float sP[62 * 64];
  __shared__ float stv[620];
  __shared__ int   sti[620];
  const int b = blockIdx.x, tid = threadIdx.x;
  const int lane = tid & 63, wave = tid >> 6;

  const float* gp = GP + (size_t)b * 62 * 96;
  for (int i = tid; i < 62 * 96; i += 256) {
    const int e = i / 96, q = i - e * 96;
    const float v = gp[i];
    if (q < 32) sG[e * 33 + q] = v; else sP[e * 64 + (q - 32)] = v;
  }
  __syncthreads();

  for (int e = wave; e < E_NODES; e += 4) {
    float sc = -1e30f;
    if (lane < E_NODES) {
      float s = 0.f;
#pragma unroll
      for (int k = 0; k < 32; ++k) s += sG[e * 33 + k] * sG[lane * 33 + k];
      sc = s;
    }
    float mx = sc;
#pragma unroll
    for (int off = 32; off; off >>= 1) mx = fmaxf(mx, __shfl_xor(mx, off));
    float p = (lane < E_NODES) ? __expf(sc - mx) : 0.f;
    float sum = p;
#pragma unroll
    for (int off = 32; off; off >>= 1) sum += __shfl_xor(sum, off);
    p = p / sum;
    float v = (lane < E_NODES) ? p : -1.f;
#pragma unroll 1
    for (int it = 0; it < TOPK; ++it) {
      float bv = v; int bi = lane;
#pragma unroll
      for (int off = 32; off; off >>= 1) {
        const float ov = __shfl_xor(bv, off);
        const int   oi = __shfl_xor(bi, off);
        if (ov > bv || (ov == bv && oi < bi)) { bv = ov; bi = oi; }  // lax.top_k tie-break
      }
      if (lane == 0) { stv[e * 10 + it] = bv; sti[e * 10 + it] = bi; }
      if (lane == bi) v = -1.f;
    }
  }
  __syncthreads();

  for (int e = wave; e < E_NODES; e += 4) {
    float acc = gcb[lane];
#pragma unroll
    for (int j = 0; j < TOPK; ++j)
      acc += stv[e * 10 + j] * sP[sti[e * 10 + j] * 64 + lane];
    Hout[((size_t)b * E_NODES + e) * 64 + lane] = fmaxf(acc, 0.f);
  }
}

// ================= SOGC layers 2/3 (DIN=64), cls fused into layer 3 =================
template <bool CLS>
__global__ __launch_bounds__(256) void sogc64_kernel(
    const float* __restrict__ Hin, const float* __restrict__ Wbn,
    const float* __restrict__ gcw, const float* __restrict__ gcb,
    const float* __restrict__ cw, const float* __restrict__ cb,
    float* __restrict__ outbuf)   // Hout (b,62,64) or logits (b,4)
{
  extern __shared__ float sm[];
  float* sH  = sm;                 // 62*65 = 4030
  float* sWt = sm + 4030;          // 64*97 = 6208
  float* sG  = sm + 10238;         // 62*33 = 2046
  float* sP  = sm + 12284;         // 62*64 = 3968
  float* stv = sm + 16252;         // 620
  int*   sti = (int*)(sm + 16872); // 620
  float* sred = sm + 17492;        // 16

  const int b = blockIdx.x, tid = threadIdx.x;
  const int lane = tid & 63, wave = tid >> 6;

  const float* Hb = Hin + (size_t)b * 62 * 64;
  for (int i = tid; i < 62 * 64; i += 256)
    sH[(i >> 6) * 65 + (i & 63)] = Hb[i];
  for (int i = tid; i < 64 * 64; i += 256)        // gcw (o,d) -> sWt[d][o]
    sWt[(i & 63) * 97 + (i >> 6)] = gcw[i];
  for (int i = tid; i < 32 * 64; i += 256)        // Wbn (k,d) -> sWt[d][64+k]
    sWt[(i & 63) * 97 + 64 + (i >> 6)] = Wbn[i];
  __syncthreads();

  for (int e = wave; e < E_NODES; e += 4) {
    const float* hrow = sH + e * 65;
    const float* wp = sWt + lane;
    const float* wg = sWt + 64 + (lane & 31);
    float accp = 0.f, accg = 0.f;
#pragma unroll 8
    for (int d = 0; d < 64; ++d) {
      const float h = hrow[d];
      accp += h * wp[d * 97];
      accg += h * wg[d * 97];
    }
    sP[e * 64 + lane] = accp;
    if (lane < 32) sG[e * 33 + lane] = 1.f - 2.f / (__expf(2.f * accg) + 1.f);
  }
  __syncthreads();

  for (int e = wave; e < E_NODES; e += 4) {
    float sc = -1e30f;
    if (lane < E_NODES) {
      float s = 0.f;
#pragma unroll
      for (int k = 0; k < 32; ++k) s += sG[e * 33 + k] * sG[lane * 33 + k];
      sc = s;
    }
    float mx = sc;
#pragma unroll
    for (int off = 32; off; off >>= 1) mx = fmaxf(mx, __shfl_xor(mx, off));
    float p = (lane < E_NODES) ? __expf(sc - mx) : 0.f;
    float sum = p;
#pragma unroll
    for (int off = 32; off; off >>= 1) sum += __shfl_xor(sum, off);
    p = p / sum;
    float v = (lane < E_NODES) ? p : -1.f;
#pragma unroll 1
    for (int it = 0; it < TOPK; ++it) {
      float bv = v; int bi = lane;
#pragma unroll
      for (int off = 32; off; off >>= 1) {
        const float ov = __shfl_xor(bv, off);
        const int   oi = __shfl_xor(bi, off);
        if (ov > bv || (ov == bv && oi < bi)) { bv = ov; bi = oi; }
      }
      if (lane == 0) { stv[e * 10 + it] = bv; sti[e * 10 + it] = bi; }
      if (lane == bi) v = -1.f;
    }
  }
  __syncthreads();

  float accn[4] = {0.f, 0.f, 0.f, 0.f};
  for (int e = wave; e < E_NODES; e += 4) {
    float acc = gcb[lane];
#pragma unroll
    for (int j = 0; j < TOPK; ++j)
      acc += stv[e * 10 + j] * sP[sti[e * 10 + j] * 64 + lane];
    acc = fmaxf(acc, 0.f);
    if (CLS) {
#pragma unroll
      for (int n = 0; n < 4; ++n)
        accn[n] += acc * cw[n * 3968 + e * 64 + lane];
    } else {
      outbuf[((size_t)b * E_NODES + e) * 64 + lane] = acc;
    }
  }
  if (CLS) {
#pragma unroll
    for (int n = 0; n < 4; ++n) {
      float s = accn[n];
#pragma unroll
      for (int off = 32; off; off >>= 1) s += __shfl_xor(s, off);
      if (lane == 0) sred[wave * 4 + n] = s;
    }
    __syncthreads();
    if (tid < 4)
      outbuf[b * 4 + tid] = cb[tid] + sred[tid] + sred[4 + tid] + sred[8 + tid] + sred[12 + tid];
  }
}

// ================= launch =================
extern "C" void kernel_launch(void* const* d_in, const int* in_sizes, int n_in,
                              void* d_out, int out_size, void* d_ws, size_t ws_size,
                              hipStream_t stream) {
  const float* x    = (const float*)d_in[0];
  const float* c1w  = (const float*)d_in[1];
  const float* c1b  = (const float*)d_in[2];
  const float* c2w  = (const float*)d_in[3];
  const float* c2b  = (const float*)d_in[4];
  const float* c3w  = (const float*)d_in[5];
  const float* c3b  = (const float*)d_in[6];
  const float* Wbn1 = (const float*)d_in[7];
  const float* gc1w = (const float*)d_in[8];
  const float* gc1b = (const float*)d_in[9];
  const float* Wbn2 = (const float*)d_in[10];
  const float* gc2w = (const float*)d_in[11];
  const float* gc2b = (const float*)d_in[12];
  const float* Wbn3 = (const float*)d_in[13];
  const float* gc3w = (const float*)d_in[14];
  const float* gc3b = (const float*)d_in[15];
  const float* clsw = (const float*)d_in[16];
  const float* clsb = (const float*)d_in[17];
  float* out = (float*)d_out;

  float* wsf = (float*)d_ws;
  float* W2T = wsf;                         // 10240
  float* W3T = wsf + 10240;                 // 40960
  float* H3  = wsf + 51200;                 // 31744*512 = 16,252,928
  float* GP  = H3 + (size_t)16252928;       // 31744*96
  float* Hs1 = GP + (size_t)3047424;        // 512*62*64
  float* Hs2 = Hs1 + (size_t)2031616;       // total ~93.2 MB

  const int SOGC64_BYTES = 17508 * 4;       // 70,032 B dynamic LDS

  (void)hipFuncSetAttribute((const void*)sogc64_kernel<false>,
                            hipFuncAttributeMaxDynamicSharedMemorySize, SOGC64_BYTES);
  (void)hipFuncSetAttribute((const void*)sogc64_kernel<true>,
                            hipFuncAttributeMaxDynamicSharedMemorySize, SOGC64_BYTES);

  wt_kernel<<<200, 256, 0, stream>>>(c2w, c3w, W2T, W3T);
  conv_chain_kernel<<<7936, 256, 0, stream>>>(x, c1w, c1b, W2T, c2b, W3T, c3b, H3);
  gp_kernel<<<992, 256, 0, stream>>>(H3, Wbn1, gc1w, GP);
  sogc1_kernel<<<512, 256, 0, stream>>>(GP, gc1b, Hs1);
  sogc64_kernel<false><<<512, 256, SOGC64_BYTES, stream>>>(
      Hs1, Wbn2, gc2w, gc2b, nullptr, nullptr, Hs2);
  sogc64_kernel<true><<<512, 256, SOGC64_BYTES, stream>>>(
      Hs2, Wbn3, gc3w, gc3b, clsw, clsb, out);
}

// Round 9
// 1167.249 us; speedup vs baseline: 3.3537x; 1.0096x over previous
//
#include <hip/hip_runtime.h>

#define E_NODES 62
#define TOPK 10
// conv geometry: (5,64) -> c1 5x5 -> (1,60) -> pool -> 30
//                -> c2 1x5 (64ch) -> 26 -> pool -> 13
//                -> c3 1x5 (128ch) -> 9 -> pool -> 4 (pos 8 unused)

// ---- weight reshape: w2t(160,64), w3t(320,128),
// WT4[d4][j][q] = (j<32 ? Wbn1[j][4*d4+q] : gc1w[j-32][4*d4+q])  (49152 fl)
__global__ __launch_bounds__(256) void wt_kernel(
    const float* __restrict__ w2, const float* __restrict__ w3,
    const float* __restrict__ Wbn1, const float* __restrict__ gc1w,
    float* __restrict__ w2t, float* __restrict__ w3t, float* __restrict__ wt)
{
  const int j = blockIdx.x * 256 + threadIdx.x;
  if (j < 10240) {
    const int r = j >> 6, o = j & 63;
    w2t[j] = w2[o * 160 + r];
  } else if (j < 51200) {
    const int k = j - 10240;               // < 40960
    const int r = k >> 7, o = k & 127;
    w3t[k] = w3[o * 320 + r];
  } else {
    const int k = j - 51200;               // < 49152
    const int d4 = k / 384, rem = k - d4 * 384;
    const int jj = rem >> 2, q = rem & 3;
    const int d = d4 * 4 + q;
    wt[k] = (jj < 32) ? Wbn1[jj * 512 + d] : gc1w[(jj - 32) * 512 + d];
  }
}

// async global->LDS, 16B/lane; n4 = count of float4
__device__ __forceinline__ void stage16(const float* __restrict__ g,
                                        float* l, int n4, int tid) {
  for (int i = tid; i < n4; i += 256)
    __builtin_amdgcn_global_load_lds(
        (const __attribute__((address_space(1))) void*)(g + 4 * i),
        (__attribute__((address_space(3))) void*)(l + 4 * i), 16, 0, 0);
}

// ================= fused conv chain + GP tail =================
// 256 threads / block, 4 images (wave = image). Writes GP (31744,96).
// LDS floats: h1[4][32][32]@0 | h2[4][64][16]@4096 | wA@8192(2560) wB@10752(2560)
//   conv1 w+b (832) + img (1280) alias wA; GP tail: WT4 slices (32 d = 3072 fl
//   <= 4096 zone — round-8 bug was 6144-fl slices overflowing the zones),
//   dbuf h1-zone/h2-zone; pooled h3[4][520] in wB zone.
// Total 13312 fl = 53248 B -> 3 blocks/CU.
// __launch_bounds__(256,3): unified file 512/wave -> cap ~170; live ~60.

__global__ __launch_bounds__(256, 3) void conv_chain_kernel(
    const float* __restrict__ x,
    const float* __restrict__ w1, const float* __restrict__ b1,
    const float* __restrict__ w2t, const float* __restrict__ b2,
    const float* __restrict__ w3t, const float* __restrict__ b3,
    const float* __restrict__ WT, float* __restrict__ GP)
{
  __shared__ float sm[13312];
  float* s_h1  = sm;            // 4*32*32 (pitch 32)
  float* s_h2  = sm + 4096;     // 4*64*16 (pitch 16)
  float* s_wa  = sm + 8192;     // 2560
  float* s_wb  = sm + 10752;    // 2560
  float* s_w1  = sm + 8192;     // conv1 w(800)+b(32), aliases wA
  float* s_img = sm + 9024;     // 1280, aliases wA

  const int tid = threadIdx.x;
  const int n0 = blockIdx.x * 4;
  const int im = tid >> 6;
  const int lane = tid & 63;

  stage16(x + (size_t)n0 * 320, s_img, 320, tid);
  for (int i = tid; i < 832; i += 256) s_w1[i] = (i < 800) ? w1[i] : b1[i - 800];
  __syncthreads();

  // stage conv2 chunk 0 -> wB during conv1 compute
  stage16(w2t, s_wb, 640, tid);

  // ---- conv1 + relu + pool. lane = (half, tp): stride-1 writes (no conflict)
  {
    const int tp = lane & 31;        // pooled position, 0..29 used
    const int half = lane >> 5;      // output-channel half
    if (tp < 30) {
      const float* ib = s_img + im * 320;
      const int t0 = 2 * tp;
      float r[5][6];
#pragma unroll
      for (int kr = 0; kr < 5; ++kr)
#pragma unroll
        for (int c = 0; c < 6; ++c) r[kr][c] = ib[kr * 64 + t0 + c];
#pragma unroll 4
      for (int oi = 0; oi < 16; ++oi) {
        const int o = half * 16 + oi;
        const float* w = s_w1 + o * 25;       // 2-address broadcast reads
        float s0 = s_w1[800 + o], s1 = s0;
#pragma unroll
        for (int kr = 0; kr < 5; ++kr) {
#pragma unroll
          for (int k = 0; k < 5; ++k) {       // pure v_fmac form
            const float wv = w[kr * 5 + k];
            s0 += r[kr][k] * wv;
            s1 += r[kr][k + 1] * wv;
          }
        }
        s_h1[im * 1024 + o * 32 + tp] = fmaxf(fmaxf(s0, s1), 0.f);
      }
    }
  }
  __syncthreads();   // h1 ready; conv2 chunk0 staged (vmcnt drained)

  // ---- conv2 + relu + pool: thread = (im, o). T-TILED (7+6) for reg pressure.
  {
    const int o = lane;
    const float bia = b2[o];

    // tile 0: pooled t = 0..6 (inputs 0..17)
    {
      float acc0[7], acc1[7];
#pragma unroll
      for (int t = 0; t < 7; ++t) { acc0[t] = bia; acc1[t] = bia; }
#pragma unroll 1
      for (int c = 0; c < 4; ++c) {
        const float* rb = (c & 1) ? s_wa : s_wb;
        float*       nb = (c & 1) ? s_wb : s_wa;
        stage16(w2t + ((c < 3) ? (c + 1) * 2560 : 0), nb, 640, tid);
#pragma unroll 4
        for (int cl = 0; cl < 8; ++cl) {
          const float* hr = s_h1 + im * 1024 + (c * 8 + cl) * 32;  // broadcast
          float r[18];
#pragma unroll
          for (int q = 0; q < 4; ++q) {
            const float4 v = *(const float4*)(hr + q * 4);
            r[q * 4] = v.x; r[q * 4 + 1] = v.y; r[q * 4 + 2] = v.z; r[q * 4 + 3] = v.w;
          }
          { const float2 v = *(const float2*)(hr + 16); r[16] = v.x; r[17] = v.y; }
          const float* wb = rb + cl * 320 + o;         // (cl*5+k)*64+o, imm offsets
#pragma unroll
          for (int k = 0; k < 5; ++k) {
            const float wv = wb[k * 64];
#pragma unroll
            for (int t = 0; t < 7; ++t) {              // pure v_fmac
              acc0[t] += r[2 * t + k] * wv;
              acc1[t] += r[2 * t + 1 + k] * wv;
            }
          }
        }
        __syncthreads();    // next chunk staged + all reads of rb done
      }
#pragma unroll
      for (int t = 0; t < 7; ++t)
        s_h2[im * 1024 + o * 16 + t] = fmaxf(fmaxf(acc0[t], acc1[t]), 0.f);
    }

    // tile 1: pooled t = 7..12 (inputs 14..29; r[j] = input[12+j])
    {
      float acc0[6], acc1[6];
#pragma unroll
      for (int t = 0; t < 6; ++t) { acc0[t] = bia; acc1[t] = bia; }
#pragma unroll 1
      for (int c = 0; c < 4; ++c) {
        const float* rb = (c & 1) ? s_wa : s_wb;
        float*       nb = (c & 1) ? s_wb : s_wa;
        // next: tile1 chunk c+1, else conv3 chunk 0
        stage16((c < 3) ? (w2t + (c + 1) * 2560) : w3t, nb, 640, tid);
#pragma unroll 4
        for (int cl = 0; cl < 8; ++cl) {
          const float* hr = s_h1 + im * 1024 + (c * 8 + cl) * 32;
          float r[18];
#pragma unroll
          for (int q = 0; q < 4; ++q) {
            const float4 v = *(const float4*)(hr + 12 + q * 4);
            r[q * 4] = v.x; r[q * 4 + 1] = v.y; r[q * 4 + 2] = v.z; r[q * 4 + 3] = v.w;
          }
          { const float2 v = *(const float2*)(hr + 28); r[16] = v.x; r[17] = v.y; }
          const float* wb = rb + cl * 320 + o;
#pragma unroll
          for (int k = 0; k < 5; ++k) {
            const float wv = wb[k * 64];
#pragma unroll
            for (int t = 0; t < 6; ++t) {
              const int t0 = 2 * t + 2;                // input[2(t+7)] local
              acc0[t] += r[t0 + k] * wv;
              acc1[t] += r[t0 + 1 + k] * wv;
            }
          }
        }
        __syncthreads();
      }
#pragma unroll
      for (int t = 0; t < 6; ++t)
        s_h2[im * 1024 + o * 16 + 7 + t] = fmaxf(fmaxf(acc0[t], acc1[t]), 0.f);
    }
  }

  // stage WT slice 0 (3072 fl <= 4096 h1 zone); h1 dead after conv2.
  // Drains at conv3's first barrier.
  stage16(WT, s_h1, 768, tid);

  // ---- conv3 + relu + pool -> pooled h3 in wB zone. 2-oc tile (lane, lane+64).
  {
    const int oc = lane;
    float acc[2][8];
#pragma unroll
    for (int t = 0; t < 8; ++t) {
      acc[0][t] = b3[oc];
      acc[1][t] = b3[64 + oc];
    }
#pragma unroll 1
    for (int k = 0; k < 16; ++k) {
      const float* rb = (k & 1) ? s_wa : s_wb;
      float*       nb = (k & 1) ? s_wb : s_wa;
      if (k < 15) stage16(w3t + (k + 1) * 2560, nb, 640, tid);
#pragma unroll 2
      for (int cl = 0; cl < 4; ++cl) {
        const float* hr = s_h2 + im * 1024 + (k * 4 + cl) * 16;  // broadcast
        float r[12];
#pragma unroll
        for (int q = 0; q < 3; ++q) {
          const float4 v = *(const float4*)(hr + q * 4);
          r[q * 4] = v.x; r[q * 4 + 1] = v.y; r[q * 4 + 2] = v.z; r[q * 4 + 3] = v.w;
        }
        const float* wb = rb + cl * 640 + oc;          // (cl*5+kk)*128+oc
#pragma unroll
        for (int kk = 0; kk < 5; ++kk) {
          const float wv0 = wb[kk * 128];
          const float wv1 = wb[kk * 128 + 64];
#pragma unroll
          for (int t = 0; t < 8; ++t) {                // pure v_fmac
            acc[0][t] += r[t + kk] * wv0;
            acc[1][t] += r[t + kk] * wv1;
          }
        }
      }
      __syncthreads();
    }
    // pooled h3 (512/image) -> wB zone (free: last wB read is k=14)
    float* h3w = s_wb + im * 520;
    float4 ov;
    ov.x = fmaxf(fmaxf(acc[0][0], acc[0][1]), 0.f);
    ov.y = fmaxf(fmaxf(acc[0][2], acc[0][3]), 0.f);
    ov.z = fmaxf(fmaxf(acc[0][4], acc[0][5]), 0.f);
    ov.w = fmaxf(fmaxf(acc[0][6], acc[0][7]), 0.f);
    *(float4*)(h3w + oc * 4) = ov;
    ov.x = fmaxf(fmaxf(acc[1][0], acc[1][1]), 0.f);
    ov.y = fmaxf(fmaxf(acc[1][2], acc[1][3]), 0.f);
    ov.z = fmaxf(fmaxf(acc[1][4], acc[1][5]), 0.f);
    ov.w = fmaxf(fmaxf(acc[1][6], acc[1][7]), 0.f);
    *(float4*)(h3w + 256 + oc * 4) = ov;
  }

  // ---- GP tail: gp[j<32] = tanh(Wbn1.h), gp[32+o] = gc1w[o].h
  // 16 slices of 32 d (8 d4-groups, 3072 fl each); slice s in zone
  // (s&1 ? h2 : h1); stage s+2 into zone freed at barrier s (drains at
  // barrier s+1, read at s+2). All reads ds_read_b128.
  {
    stage16(WT + 3072, s_h2, 768, tid);    // slice 1 (h2 dead post-conv3)
    __syncthreads();                       // h3 visible; slices 0,1 drained
    const float* h3 = s_wb + im * 520;
    const int jP = 32 + lane, jG = lane & 31;
    float accp = 0.f, accg = 0.f;
#pragma unroll 1
    for (int s = 0; s < 16; ++s) {
      const float* z = (s & 1) ? s_h2 : s_h1;
#pragma unroll
      for (int d4 = 0; d4 < 8; ++d4) {
        const float4 hv = *(const float4*)(h3 + s * 32 + d4 * 4);   // broadcast
        const float4 wp = *(const float4*)(z + d4 * 384 + jP * 4);  // b128
        const float4 wg = *(const float4*)(z + d4 * 384 + jG * 4);  // b128
        accp += hv.x * wp.x + hv.y * wp.y + hv.z * wp.z + hv.w * wp.w;
        accg += hv.x * wg.x + hv.y * wg.y + hv.z * wg.z + hv.w * wg.w;
      }
      __syncthreads();                               // zone reads done
      if (s < 14) stage16(WT + (s + 2) * 3072, (s & 1) ? s_h2 : s_h1, 768, tid);
    }
    float* gpo = GP + (size_t)(n0 + im) * 96;
    gpo[32 + lane] = accp;
    if (lane < 32) gpo[lane] = 1.f - 2.f / (__expf(2.f * accg) + 1.f);
  }
}

// ================= SOGC layer 1 (consumes GP) =================
__global__ __launch_bounds__(256) void sogc1_kernel(
    const float* __restrict__ GP, const float* __restrict__ gcb,
    float* __restrict__ Hout)
{
  __shared__ float sG[62 * 33];
  __shared__ float sP[62 * 64];
  __shared__ float stv[620];
  __shared__ int   sti[620];
  const int b = blockIdx.x, tid = threadIdx.x;
  const int lane = tid & 63, wave = tid >> 6;

  const float* gp = GP + (size_t)b * 62 * 96;
  for (int i = tid; i < 62 * 96; i += 256) {
    const int e = i / 96, q = i - e * 96;
    const float v = gp[i];
    if (q < 32) sG[e * 33 + q] = v; else sP[e * 64 + (q - 32)] = v;
  }
  __syncthreads();

  for (int e = wave; e < E_NODES; e += 4) {
    float sc = -1e30f;
    if (lane < E_NODES) {
      float s = 0.f;
#pragma unroll
      for (int k = 0; k < 32; ++k) s += sG[e * 33 + k] * sG[lane * 33 + k];
      sc = s;
    }
    float mx = sc;
#pragma unroll
    for (int off = 32; off; off >>= 1) mx = fmaxf(mx, __shfl_xor(mx, off));
    float p = (lane < E_NODES) ? __expf(sc - mx) : 0.f;
    float sum = p;
#pragma unroll
    for (int off = 32; off; off >>= 1) sum += __shfl_xor(sum, off);
    p = p / sum;
    float v = (lane < E_NODES) ? p : -1.f;
#pragma unroll 1
    for (int it = 0; it < TOPK; ++it) {
      float bv = v; int bi = lane;
#pragma unroll
      for (int off = 32; off; off >>= 1) {
        const float ov = __shfl_xor(bv, off);
        const int   oi = __shfl_xor(bi, off);
        if (ov > bv || (ov == bv && oi < bi)) { bv = ov; bi = oi; }  // lax.top_k tie-break
      }
      if (lane == 0) { stv[e * 10 + it] = bv; sti[e * 10 + it] = bi; }
      if (lane == bi) v = -1.f;
    }
  }
  __syncthreads();

  for (int e = wave; e < E_NODES; e += 4) {
    float acc = gcb[lane];
#pragma unroll
    for (int j = 0; j < TOPK; ++j)
      acc += stv[e * 10 + j] * sP[sti[e * 10 + j] * 64 + lane];
    Hout[((size_t)b * E_NODES + e) * 64 + lane] = fmaxf(acc, 0.f);
  }
}

// ================= SOGC layers 2/3 (DIN=64), cls fused into layer 3 =================
template <bool CLS>
__global__ __launch_bounds__(256) void sogc64_kernel(
    const float* __restrict__ Hin, const float* __restrict__ Wbn,
    const float* __restrict__ gcw, const float* __restrict__ gcb,
    const float* __restrict__ cw, const float* __restrict__ cb,
    float* __restrict__ outbuf)   // Hout (b,62,64) or logits (b,4)
{
  extern __shared__ float sm[];
  float* sH  = sm;                 // 62*65 = 4030
  float* sWt = sm + 4030;          // 64*97 = 6208
  float* sG  = sm + 10238;         // 62*33 = 2046
  float* sP  = sm + 12284;         // 62*64 = 3968
  float* stv = sm + 16252;         // 620
  int*   sti = (int*)(sm + 16872); // 620
  float* sred = sm + 17492;        // 16

  const int b = blockIdx.x, tid = threadIdx.x;
  const int lane = tid & 63, wave = tid >> 6;

  const float* Hb = Hin + (size_t)b * 62 * 64;
  for (int i = tid; i < 62 * 64; i += 256)
    sH[(i >> 6) * 65 + (i & 63)] = Hb[i];
  for (int i = tid; i < 64 * 64; i += 256)        // gcw (o,d) -> sWt[d][o]
    sWt[(i & 63) * 97 + (i >> 6)] = gcw[i];
  for (int i = tid; i < 32 * 64; i += 256)        // Wbn (k,d) -> sWt[d][64+k]
    sWt[(i & 63) * 97 + 64 + (i >> 6)] = Wbn[i];
  __syncthreads();

  for (int e = wave; e < E_NODES; e += 4) {
    const float* hrow = sH + e * 65;
    const float* wp = sWt + lane;
    const float* wg = sWt + 64 + (lane & 31);
    float accp = 0.f, accg = 0.f;
#pragma unroll 8
    for (int d = 0; d < 64; ++d) {
      const float h = hrow[d];
      accp += h * wp[d * 97];
      accg += h * wg[d * 97];
    }
    sP[e * 64 + lane] = accp;
    if (lane < 32) sG[e * 33 + lane] = 1.f - 2.f / (__expf(2.f * accg) + 1.f);
  }
  __syncthreads();

  for (int e = wave; e < E_NODES; e += 4) {
    float sc = -1e30f;
    if (lane < E_NODES) {
      float s = 0.f;
#pragma unroll
      for (int k = 0; k < 32; ++k) s += sG[e * 33 + k] * sG[lane * 33 + k];
      sc = s;
    }
    float mx = sc;
#pragma unroll
    for (int off = 32; off; off >>= 1) mx = fmaxf(mx, __shfl_xor(mx, off));
    float p = (lane < E_NODES) ? __expf(sc - mx) : 0.f;
    float sum = p;
#pragma unroll
    for (int off = 32; off; off >>= 1) sum += __shfl_xor(sum, off);
    p = p / sum;
    float v = (lane < E_NODES) ? p : -1.f;
#pragma unroll 1
    for (int it = 0; it < TOPK; ++it) {
      float bv = v; int bi = lane;
#pragma unroll
      for (int off = 32; off; off >>= 1) {
        const float ov = __shfl_xor(bv, off);
        const int   oi = __shfl_xor(bi, off);
        if (ov > bv || (ov == bv && oi < bi)) { bv = ov; bi = oi; }
      }
      if (lane == 0) { stv[e * 10 + it] = bv; sti[e * 10 + it] = bi; }
      if (lane == bi) v = -1.f;
    }
  }
  __syncthreads();

  float accn[4] = {0.f, 0.f, 0.f, 0.f};
  for (int e = wave; e < E_NODES; e += 4) {
    float acc = gcb[lane];
#pragma unroll
    for (int j = 0; j < TOPK; ++j)
      acc += stv[e * 10 + j] * sP[sti[e * 10 + j] * 64 + lane];
    acc = fmaxf(acc, 0.f);
    if (CLS) {
#pragma unroll
      for (int n = 0; n < 4; ++n)
        accn[n] += acc * cw[n * 3968 + e * 64 + lane];
    } else {
      outbuf[((size_t)b * E_NODES + e) * 64 + lane] = acc;
    }
  }
  if (CLS) {
#pragma unroll
    for (int n = 0; n < 4; ++n) {
      float s = accn[n];
#pragma unroll
      for (int off = 32; off; off >>= 1) s += __shfl_xor(s, off);
      if (lane == 0) sred[wave * 4 + n] = s;
    }
    __syncthreads();
    if (tid < 4)
      outbuf[b * 4 + tid] = cb[tid] + sred[tid] + sred[4 + tid] + sred[8 + tid] + sred[12 + tid];
  }
}

// ================= launch =================
extern "C" void kernel_launch(void* const* d_in, const int* in_sizes, int n_in,
                              void* d_out, int out_size, void* d_ws, size_t ws_size,
                              hipStream_t stream) {
  const float* x    = (const float*)d_in[0];
  const float* c1w  = (const float*)d_in[1];
  const float* c1b  = (const float*)d_in[2];
  const float* c2w  = (const float*)d_in[3];
  const float* c2b  = (const float*)d_in[4];
  const float* c3w  = (const float*)d_in[5];
  const float* c3b  = (const float*)d_in[6];
  const float* Wbn1 = (const float*)d_in[7];
  const float* gc1w = (const float*)d_in[8];
  const float* gc1b = (const float*)d_in[9];
  const float* Wbn2 = (const float*)d_in[10];
  const float* gc2w = (const float*)d_in[11];
  const float* gc2b = (const float*)d_in[12];
  const float* Wbn3 = (const float*)d_in[13];
  const float* gc3w = (const float*)d_in[14];
  const float* gc3b = (const float*)d_in[15];
  const float* clsw = (const float*)d_in[16];
  const float* clsb = (const float*)d_in[17];
  float* out = (float*)d_out;

  float* wsf = (float*)d_ws;
  float* W2T = wsf;                         // 10240
  float* W3T = wsf + 10240;                 // 40960
  float* WT  = wsf + 51200;                 // 49152 (WT4 layout)
  float* GP  = wsf + 100352;                // 31744*96 = 3,047,424
  float* Hs1 = GP + (size_t)3047424;        // 512*62*64 = 2,031,616
  float* Hs2 = Hs1 + (size_t)2031616;       // total ~29 MB

  const int SOGC64_BYTES = 17508 * 4;       // 70,032 B dynamic LDS

  (void)hipFuncSetAttribute((const void*)sogc64_kernel<false>,
                            hipFuncAttributeMaxDynamicSharedMemorySize, SOGC64_BYTES);
  (void)hipFuncSetAttribute((const void*)sogc64_kernel<true>,
                            hipFuncAttributeMaxDynamicSharedMemorySize, SOGC64_BYTES);

  wt_kernel<<<392, 256, 0, stream>>>(c2w, c3w, Wbn1, gc1w, W2T, W3T, WT);
  conv_chain_kernel<<<7936, 256, 0, stream>>>(x, c1w, c1b, W2T, c2b, W3T, c3b,
                                              WT, GP);
  sogc1_kernel<<<512, 256, 0, stream>>>(GP, gc1b, Hs1);
  sogc64_kernel<false><<<512, 256, SOGC64_BYTES, stream>>>(
      Hs1, Wbn2, gc2w, gc2b, nullptr, nullptr, Hs2);
  sogc64_kernel<true><<<512, 256, SOGC64_BYTES, stream>>>(
      Hs2, Wbn3, gc3w, gc3b, clsw, clsb, out);
}

// Round 10
// 1147.478 us; speedup vs baseline: 3.4115x; 1.0172x over previous
//
#include <hip/hip_runtime.h>

#define E_NODES 62
#define TOPK 10
// conv geometry: (5,64) -> c1 5x5 -> (1,60) -> pool -> 30
//                -> c2 1x5 (64ch) -> 26 -> pool -> 13
//                -> c3 1x5 (128ch) -> 9 -> pool -> 4 (pos 8 unused)

// ---- weight reshape: w2t(160,64), w3t(320,128),
// WT4[d4][j][q] = (j<32 ? Wbn1[j][4*d4+q] : gc1w[j-32][4*d4+q])  (49152 fl)
__global__ __launch_bounds__(256) void wt_kernel(
    const float* __restrict__ w2, const float* __restrict__ w3,
    const float* __restrict__ Wbn1, const float* __restrict__ gc1w,
    float* __restrict__ w2t, float* __restrict__ w3t, float* __restrict__ wt)
{
  const int j = blockIdx.x * 256 + threadIdx.x;
  if (j < 10240) {
    const int r = j >> 6, o = j & 63;
    w2t[j] = w2[o * 160 + r];
  } else if (j < 51200) {
    const int k = j - 10240;               // < 40960
    const int r = k >> 7, o = k & 127;
    w3t[k] = w3[o * 320 + r];
  } else {
    const int k = j - 51200;               // < 49152
    const int d4 = k / 384, rem = k - d4 * 384;
    const int jj = rem >> 2, q = rem & 3;
    const int d = d4 * 4 + q;
    wt[k] = (jj < 32) ? Wbn1[jj * 512 + d] : gc1w[(jj - 32) * 512 + d];
  }
}

// async global->LDS, 16B/lane; n4 = count of float4
__device__ __forceinline__ void stage16(const float* __restrict__ g,
                                        float* l, int n4, int tid) {
  for (int i = tid; i < n4; i += 256)
    __builtin_amdgcn_global_load_lds(
        (const __attribute__((address_space(1))) void*)(g + 4 * i),
        (__attribute__((address_space(3))) void*)(l + 4 * i), 16, 0, 0);
}

// ================= fused conv chain + GP tail =================
// (verified structure, round 9: 890 us, VGPR 84, no spill)
__global__ __launch_bounds__(256, 3) void conv_chain_kernel(
    const float* __restrict__ x,
    const float* __restrict__ w1, const float* __restrict__ b1,
    const float* __restrict__ w2t, const float* __restrict__ b2,
    const float* __restrict__ w3t, const float* __restrict__ b3,
    const float* __restrict__ WT, float* __restrict__ GP)
{
  __shared__ float sm[13312];
  float* s_h1  = sm;            // 4*32*32 (pitch 32)
  float* s_h2  = sm + 4096;     // 4*64*16 (pitch 16)
  float* s_wa  = sm + 8192;     // 2560
  float* s_wb  = sm + 10752;    // 2560
  float* s_w1  = sm + 8192;     // conv1 w(800)+b(32), aliases wA
  float* s_img = sm + 9024;     // 1280, aliases wA

  const int tid = threadIdx.x;
  const int n0 = blockIdx.x * 4;
  const int im = tid >> 6;
  const int lane = tid & 63;

  stage16(x + (size_t)n0 * 320, s_img, 320, tid);
  for (int i = tid; i < 832; i += 256) s_w1[i] = (i < 800) ? w1[i] : b1[i - 800];
  __syncthreads();

  // stage conv2 chunk 0 -> wB during conv1 compute
  stage16(w2t, s_wb, 640, tid);

  // ---- conv1 + relu + pool. lane = (half, tp): stride-1 writes (no conflict)
  {
    const int tp = lane & 31;        // pooled position, 0..29 used
    const int half = lane >> 5;      // output-channel half
    if (tp < 30) {
      const float* ib = s_img + im * 320;
      const int t0 = 2 * tp;
      float r[5][6];
#pragma unroll
      for (int kr = 0; kr < 5; ++kr)
#pragma unroll
        for (int c = 0; c < 6; ++c) r[kr][c] = ib[kr * 64 + t0 + c];
#pragma unroll 4
      for (int oi = 0; oi < 16; ++oi) {
        const int o = half * 16 + oi;
        const float* w = s_w1 + o * 25;       // 2-address broadcast reads
        float s0 = s_w1[800 + o], s1 = s0;
#pragma unroll
        for (int kr = 0; kr < 5; ++kr) {
#pragma unroll
          for (int k = 0; k < 5; ++k) {       // pure v_fmac form
            const float wv = w[kr * 5 + k];
            s0 += r[kr][k] * wv;
            s1 += r[kr][k + 1] * wv;
          }
        }
        s_h1[im * 1024 + o * 32 + tp] = fmaxf(fmaxf(s0, s1), 0.f);
      }
    }
  }
  __syncthreads();   // h1 ready; conv2 chunk0 staged (vmcnt drained)

  // ---- conv2 + relu + pool: thread = (im, o). T-TILED (7+6) for reg pressure.
  {
    const int o = lane;
    const float bia = b2[o];

    // tile 0: pooled t = 0..6 (inputs 0..17)
    {
      float acc0[7], acc1[7];
#pragma unroll
      for (int t = 0; t < 7; ++t) { acc0[t] = bia; acc1[t] = bia; }
#pragma unroll 1
      for (int c = 0; c < 4; ++c) {
        const float* rb = (c & 1) ? s_wa : s_wb;
        float*       nb = (c & 1) ? s_wb : s_wa;
        stage16(w2t + ((c < 3) ? (c + 1) * 2560 : 0), nb, 640, tid);
#pragma unroll 4
        for (int cl = 0; cl < 8; ++cl) {
          const float* hr = s_h1 + im * 1024 + (c * 8 + cl) * 32;  // broadcast
          float r[18];
#pragma unroll
          for (int q = 0; q < 4; ++q) {
            const float4 v = *(const float4*)(hr + q * 4);
            r[q * 4] = v.x; r[q * 4 + 1] = v.y; r[q * 4 + 2] = v.z; r[q * 4 + 3] = v.w;
          }
          { const float2 v = *(const float2*)(hr + 16); r[16] = v.x; r[17] = v.y; }
          const float* wb = rb + cl * 320 + o;         // (cl*5+k)*64+o, imm offsets
#pragma unroll
          for (int k = 0; k < 5; ++k) {
            const float wv = wb[k * 64];
#pragma unroll
            for (int t = 0; t < 7; ++t) {              // pure v_fmac
              acc0[t] += r[2 * t + k] * wv;
              acc1[t] += r[2 * t + 1 + k] * wv;
            }
          }
        }
        __syncthreads();    // next chunk staged + all reads of rb done
      }
#pragma unroll
      for (int t = 0; t < 7; ++t)
        s_h2[im * 1024 + o * 16 + t] = fmaxf(fmaxf(acc0[t], acc1[t]), 0.f);
    }

    // tile 1: pooled t = 7..12 (inputs 14..29; r[j] = input[12+j])
    {
      float acc0[6], acc1[6];
#pragma unroll
      for (int t = 0; t < 6; ++t) { acc0[t] = bia; acc1[t] = bia; }
#pragma unroll 1
      for (int c = 0; c < 4; ++c) {
        const float* rb = (c & 1) ? s_wa : s_wb;
        float*       nb = (c & 1) ? s_wb : s_wa;
        // next: tile1 chunk c+1, else conv3 chunk 0
        stage16((c < 3) ? (w2t + (c + 1) * 2560) : w3t, nb, 640, tid);
#pragma unroll 4
        for (int cl = 0; cl < 8; ++cl) {
          const float* hr = s_h1 + im * 1024 + (c * 8 + cl) * 32;
          float r[18];
#pragma unroll
          for (int q = 0; q < 4; ++q) {
            const float4 v = *(const float4*)(hr + 12 + q * 4);
            r[q * 4] = v.x; r[q * 4 + 1] = v.y; r[q * 4 + 2] = v.z; r[q * 4 + 3] = v.w;
          }
          { const float2 v = *(const float2*)(hr + 28); r[16] = v.x; r[17] = v.y; }
          const float* wb = rb + cl * 320 + o;
#pragma unroll
          for (int k = 0; k < 5; ++k) {
            const float wv = wb[k * 64];
#pragma unroll
            for (int t = 0; t < 6; ++t) {
              const int t0 = 2 * t + 2;                // input[2(t+7)] local
              acc0[t] += r[t0 + k] * wv;
              acc1[t] += r[t0 + 1 + k] * wv;
            }
          }
        }
        __syncthreads();
      }
#pragma unroll
      for (int t = 0; t < 6; ++t)
        s_h2[im * 1024 + o * 16 + 7 + t] = fmaxf(fmaxf(acc0[t], acc1[t]), 0.f);
    }
  }

  // stage WT slice 0 (3072 fl <= 4096 h1 zone); h1 dead after conv2.
  stage16(WT, s_h1, 768, tid);

  // ---- conv3 + relu + pool -> pooled h3 in wB zone. 2-oc tile (lane, lane+64).
  {
    const int oc = lane;
    float acc[2][8];
#pragma unroll
    for (int t = 0; t < 8; ++t) {
      acc[0][t] = b3[oc];
      acc[1][t] = b3[64 + oc];
    }
#pragma unroll 1
    for (int k = 0; k < 16; ++k) {
      const float* rb = (k & 1) ? s_wa : s_wb;
      float*       nb = (k & 1) ? s_wb : s_wa;
      if (k < 15) stage16(w3t + (k + 1) * 2560, nb, 640, tid);
#pragma unroll 2
      for (int cl = 0; cl < 4; ++cl) {
        const float* hr = s_h2 + im * 1024 + (k * 4 + cl) * 16;  // broadcast
        float r[12];
#pragma unroll
        for (int q = 0; q < 3; ++q) {
          const float4 v = *(const float4*)(hr + q * 4);
          r[q * 4] = v.x; r[q * 4 + 1] = v.y; r[q * 4 + 2] = v.z; r[q * 4 + 3] = v.w;
        }
        const float* wb = rb + cl * 640 + oc;          // (cl*5+kk)*128+oc
#pragma unroll
        for (int kk = 0; kk < 5; ++kk) {
          const float wv0 = wb[kk * 128];
          const float wv1 = wb[kk * 128 + 64];
#pragma unroll
          for (int t = 0; t < 8; ++t) {                // pure v_fmac
            acc[0][t] += r[t + kk] * wv0;
            acc[1][t] += r[t + kk] * wv1;
          }
        }
      }
      __syncthreads();
    }
    // pooled h3 (512/image) -> wB zone (free: last wB read is k=14)
    float* h3w = s_wb + im * 520;
    float4 ov;
    ov.x = fmaxf(fmaxf(acc[0][0], acc[0][1]), 0.f);
    ov.y = fmaxf(fmaxf(acc[0][2], acc[0][3]), 0.f);
    ov.z = fmaxf(fmaxf(acc[0][4], acc[0][5]), 0.f);
    ov.w = fmaxf(fmaxf(acc[0][6], acc[0][7]), 0.f);
    *(float4*)(h3w + oc * 4) = ov;
    ov.x = fmaxf(fmaxf(acc[1][0], acc[1][1]), 0.f);
    ov.y = fmaxf(fmaxf(acc[1][2], acc[1][3]), 0.f);
    ov.z = fmaxf(fmaxf(acc[1][4], acc[1][5]), 0.f);
    ov.w = fmaxf(fmaxf(acc[1][6], acc[1][7]), 0.f);
    *(float4*)(h3w + 256 + oc * 4) = ov;
  }

  // ---- GP tail: gp[j<32] = tanh(Wbn1.h), gp[32+o] = gc1w[o].h
  // 16 slices of 32 d (3072 fl); zone (s&1 ? h2 : h1); stage s+2 into zone
  // freed at barrier s. All reads ds_read_b128.
  {
    stage16(WT + 3072, s_h2, 768, tid);    // slice 1 (h2 dead post-conv3)
    __syncthreads();                       // h3 visible; slices 0,1 drained
    const float* h3 = s_wb + im * 520;
    const int jP = 32 + lane, jG = lane & 31;
    float accp = 0.f, accg = 0.f;
#pragma unroll 1
    for (int s = 0; s < 16; ++s) {
      const float* z = (s & 1) ? s_h2 : s_h1;
#pragma unroll
      for (int d4 = 0; d4 < 8; ++d4) {
        const float4 hv = *(const float4*)(h3 + s * 32 + d4 * 4);   // broadcast
        const float4 wp = *(const float4*)(z + d4 * 384 + jP * 4);  // b128
        const float4 wg = *(const float4*)(z + d4 * 384 + jG * 4);  // b128
        accp += hv.x * wp.x + hv.y * wp.y + hv.z * wp.z + hv.w * wp.w;
        accg += hv.x * wg.x + hv.y * wg.y + hv.z * wg.z + hv.w * wg.w;
      }
      __syncthreads();                               // zone reads done
      if (s < 14) stage16(WT + (s + 2) * 3072, (s & 1) ? s_h2 : s_h1, 768, tid);
    }
    float* gpo = GP + (size_t)(n0 + im) * 96;
    gpo[32 + lane] = accp;
    if (lane < 32) gpo[lane] = 1.f - 2.f / (__expf(2.f * accg) + 1.f);
  }
}

// ================= fused SOGC x3 + classifier =================
// One block (256 thr) per batch element b. All 3 graph layers + cls in LDS.
// LDS floats: sH[62*65]@0 | sWt[64*97]@4030 | sG[62*33]@10238 | sP[62*64]@12284
//             stv@16252 | sti@16872 | sred@17492  -> 17508 fl = 70032 B.
__global__ __launch_bounds__(256) void sogc_fused_kernel(
    const float* __restrict__ GP,   const float* __restrict__ gc1b,
    const float* __restrict__ Wbn2, const float* __restrict__ gc2w,
    const float* __restrict__ gc2b,
    const float* __restrict__ Wbn3, const float* __restrict__ gc3w,
    const float* __restrict__ gc3b,
    const float* __restrict__ cw,   const float* __restrict__ cb,
    float* __restrict__ out)
{
  extern __shared__ float sm[];
  float* sH  = sm;                 // 62*65 = 4030
  float* sWt = sm + 4030;          // 64*97 = 6208
  float* sG  = sm + 10238;         // 62*33 = 2046
  float* sP  = sm + 12284;         // 62*64 = 3968
  float* stv = sm + 16252;         // 620
  int*   sti = (int*)(sm + 16872); // 620
  float* sred = sm + 17492;        // 16

  const int b = blockIdx.x, tid = threadIdx.x;
  const int lane = tid & 63, wave = tid >> 6;

  // ---- load GP[b] -> sG,sP ; layer-2 weights -> sWt
  const float* gp = GP + (size_t)b * 62 * 96;
  for (int i = tid; i < 62 * 96; i += 256) {
    const int e = i / 96, q = i - e * 96;
    const float v = gp[i];
    if (q < 32) sG[e * 33 + q] = v; else sP[e * 64 + (q - 32)] = v;
  }
  for (int i = tid; i < 64 * 64; i += 256)        // gc2w (o,d) -> sWt[d][o]
    sWt[(i & 63) * 97 + (i >> 6)] = gc2w[i];
  for (int i = tid; i < 32 * 64; i += 256)        // Wbn2 (k,d) -> sWt[d][64+k]
    sWt[(i & 63) * 97 + 64 + (i >> 6)] = Wbn2[i];
  __syncthreads();

  // ================== the 3 layers share this macro-free structure =========
#define TOPK_PHASE()                                                          \
  for (int e = wave; e < E_NODES; e += 4) {                                   \
    float sc = -1e30f;                                                        \
    if (lane < E_NODES) {                                                     \
      float s = 0.f;                                                          \
      _Pragma("unroll")                                                       \
      for (int k = 0; k < 32; ++k) s += sG[e * 33 + k] * sG[lane * 33 + k];   \
      sc = s;                                                                 \
    }                                                                         \
    float mx = sc;                                                            \
    _Pragma("unroll")                                                         \
    for (int off = 32; off; off >>= 1) mx = fmaxf(mx, __shfl_xor(mx, off));   \
    float p = (lane < E_NODES) ? __expf(sc - mx) : 0.f;                       \
    float sum = p;                                                            \
    _Pragma("unroll")                                                         \
    for (int off = 32; off; off >>= 1) sum += __shfl_xor(sum, off);           \
    p = p / sum;                                                              \
    float v = (lane < E_NODES) ? p : -1.f;                                    \
    _Pragma("unroll 1")                                                       \
    for (int it = 0; it < TOPK; ++it) {                                       \
      float bv = v; int bi = lane;                                            \
      _Pragma("unroll")                                                       \
      for (int off = 32; off; off >>= 1) {                                    \
        const float ov = __shfl_xor(bv, off);                                 \
        const int   oi = __shfl_xor(bi, off);                                 \
        if (ov > bv || (ov == bv && oi < bi)) { bv = ov; bi = oi; }           \
      }                                                                       \
      if (lane == 0) { stv[e * 10 + it] = bv; sti[e * 10 + it] = bi; }        \
      if (lane == bi) v = -1.f;                                               \
    }                                                                         \
  }

#define GP_PHASE()                                                            \
  for (int e = wave; e < E_NODES; e += 4) {                                   \
    const float* hrow = sH + e * 65;                                          \
    const float* wp = sWt + lane;                                             \
    const float* wg = sWt + 64 + (lane & 31);                                 \
    float accp = 0.f, accg = 0.f;                                             \
    _Pragma("unroll 8")                                                       \
    for (int d = 0; d < 64; ++d) {                                            \
      const float h = hrow[d];                                                \
      accp += h * wp[d * 97];                                                 \
      accg += h * wg[d * 97];                                                 \
    }                                                                         \
    sP[e * 64 + lane] = accp;                                                 \
    if (lane < 32) sG[e * 33 + lane] = 1.f - 2.f / (__expf(2.f * accg) + 1.f);\
  }

  // ---- layer 1: topk + combine -> sH
  TOPK_PHASE();
  __syncthreads();
  for (int e = wave; e < E_NODES; e += 4) {
    float acc = gc1b[lane];
#pragma unroll
    for (int j = 0; j < TOPK; ++j)
      acc += stv[e * 10 + j] * sP[sti[e * 10 + j] * 64 + lane];
    sH[e * 65 + lane] = fmaxf(acc, 0.f);
  }
  __syncthreads();

  // ---- layer 2: G/P -> topk -> combine -> sH
  GP_PHASE();
  __syncthreads();
  // restage sWt with layer-3 weights (sWt reads done) + topk2 (reads sG)
  for (int i = tid; i < 64 * 64; i += 256)
    sWt[(i & 63) * 97 + (i >> 6)] = gc3w[i];
  for (int i = tid; i < 32 * 64; i += 256)
    sWt[(i & 63) * 97 + 64 + (i >> 6)] = Wbn3[i];
  TOPK_PHASE();
  __syncthreads();
  for (int e = wave; e < E_NODES; e += 4) {
    float acc = gc2b[lane];
#pragma unroll
    for (int j = 0; j < TOPK; ++j)
      acc += stv[e * 10 + j] * sP[sti[e * 10 + j] * 64 + lane];
    sH[e * 65 + lane] = fmaxf(acc, 0.f);
  }
  __syncthreads();

  // ---- layer 3: G/P -> topk -> combine + cls
  GP_PHASE();
  __syncthreads();
  TOPK_PHASE();
  __syncthreads();
  {
    float accn[4] = {0.f, 0.f, 0.f, 0.f};
    for (int e = wave; e < E_NODES; e += 4) {
      float acc = gc3b[lane];
#pragma unroll
      for (int j = 0; j < TOPK; ++j)
        acc += stv[e * 10 + j] * sP[sti[e * 10 + j] * 64 + lane];
      acc = fmaxf(acc, 0.f);
#pragma unroll
      for (int n = 0; n < 4; ++n)
        accn[n] += acc * cw[n * 3968 + e * 64 + lane];
    }
#pragma unroll
    for (int n = 0; n < 4; ++n) {
      float s = accn[n];
#pragma unroll
      for (int off = 32; off; off >>= 1) s += __shfl_xor(s, off);
      if (lane == 0) sred[wave * 4 + n] = s;
    }
    __syncthreads();
    if (tid < 4)
      out[b * 4 + tid] = cb[tid] + sred[tid] + sred[4 + tid] + sred[8 + tid] + sred[12 + tid];
  }
#undef TOPK_PHASE
#undef GP_PHASE
}

// ================= launch =================
extern "C" void kernel_launch(void* const* d_in, const int* in_sizes, int n_in,
                              void* d_out, int out_size, void* d_ws, size_t ws_size,
                              hipStream_t stream) {
  const float* x    = (const float*)d_in[0];
  const float* c1w  = (const float*)d_in[1];
  const float* c1b  = (const float*)d_in[2];
  const float* c2w  = (const float*)d_in[3];
  const float* c2b  = (const float*)d_in[4];
  const float* c3w  = (const float*)d_in[5];
  const float* c3b  = (const float*)d_in[6];
  const float* Wbn1 = (const float*)d_in[7];
  const float* gc1w = (const float*)d_in[8];
  const float* gc1b = (const float*)d_in[9];
  const float* Wbn2 = (const float*)d_in[10];
  const float* gc2w = (const float*)d_in[11];
  const float* gc2b = (const float*)d_in[12];
  const float* Wbn3 = (const float*)d_in[13];
  const float* gc3w = (const float*)d_in[14];
  const float* gc3b = (const float*)d_in[15];
  const float* clsw = (const float*)d_in[16];
  const float* clsb = (const float*)d_in[17];
  float* out = (float*)d_out;

  float* wsf = (float*)d_ws;
  float* W2T = wsf;                         // 10240
  float* W3T = wsf + 10240;                 // 40960
  float* WT  = wsf + 51200;                 // 49152 (WT4 layout)
  float* GP  = wsf + 100352;                // 31744*96 = 3,047,424 (~12.6 MB)

  const int SOGC_BYTES = 17508 * 4;         // 70,032 B dynamic LDS

  (void)hipFuncSetAttribute((const void*)sogc_fused_kernel,
                            hipFuncAttributeMaxDynamicSharedMemorySize, SOGC_BYTES);

  wt_kernel<<<392, 256, 0, stream>>>(c2w, c3w, Wbn1, gc1w, W2T, W3T, WT);
  conv_chain_kernel<<<7936, 256, 0, stream>>>(x, c1w, c1b, W2T, c2b, W3T, c3b,
                                              WT, GP);
  sogc_fused_kernel<<<512, 256, SOGC_BYTES, stream>>>(
      GP, gc1b, Wbn2, gc2w, gc2b, Wbn3, gc3w, gc3b, clsw, clsb, out);
}